// Round 2
// baseline (575.225 us; speedup 1.0000x reference)
//
#include <hip/hip_runtime.h>

namespace {

typedef unsigned short ushort_t;
typedef unsigned int uint_t;
typedef __attribute__((ext_vector_type(8))) short bf16x8;
typedef __attribute__((ext_vector_type(4))) float f32x4;

constexpr int N   = 50000;
constexpr int E   = 600000;
constexpr int NR  = 5;
constexpr int KIN = 768;
constexpr int H   = 128;
constexpr int RD  = 200;

__device__ inline ushort_t f2b(float f){           // fp32 -> bf16 bits, RNE
  uint_t u = __builtin_bit_cast(uint_t, f);
  uint_t r = (u + 0x7FFFu + ((u >> 16) & 1u)) >> 16;
  return (ushort_t)r;
}
__device__ inline float b2f_lo(uint_t u){ return __builtin_bit_cast(float, u << 16); }
__device__ inline float b2f_hi(uint_t u){ return __builtin_bit_cast(float, u & 0xFFFF0000u); }
__device__ inline float b2f_us(ushort_t h){ return __builtin_bit_cast(float, ((uint_t)h) << 16); }
__device__ inline uint_t cvtpk(float lo, float hi){ // 2x fp32 -> packed bf16 (RNE), 1 instr
  uint_t r;
  asm("v_cvt_pk_bf16_f32 %0, %1, %2" : "=v"(r) : "v"(lo), "v"(hi));
  return r;
}

// ---- prep: weight cvt (blocks 0..703) + zero deg (704..899) + relsc (900..901) ----
__global__ void prep_k(const float* __restrict__ l1W, const float* __restrict__ W1,
                       const float* __restrict__ R1, const float* __restrict__ W2,
                       const float* __restrict__ R2, const float* __restrict__ l2W,
                       ushort_t* __restrict__ wts, int* __restrict__ deg,
                       const float* __restrict__ rel1, const float* __restrict__ Wr1,
                       const float* __restrict__ a1, float* __restrict__ sC1,
                       const float* __restrict__ rel2, const float* __restrict__ Wr2,
                       const float* __restrict__ a2, float* __restrict__ sC2){
  constexpr int S0 = H * KIN;        // 98304
  constexpr int S1 = H * H;          // 16384
  int b = blockIdx.x, tid = threadIdx.x;
  if (b < 704){                      // weight convert: 704*256 == S0 + 5*S1 exactly
    int i = b * 256 + tid;
    float v;
    if (i < S0) v = l1W[i];
    else {
      int j = i - S0, seg = j >> 14, off = j & (S1 - 1);
      const float* srcs[5] = {W1, R1, W2, R2, l2W};
      v = srcs[seg][off];
    }
    wts[i] = f2b(v);
  } else if (b < 900){               // zero deg
    int i = (b - 704) * 256 + tid;
    if (i < N) deg[i] = 0;
  } else {                           // relation scalars, one block per layer
    int L = b - 900;
    const float* rel = L ? rel2 : rel1;
    const float* Wr  = L ? Wr2  : Wr1;
    const float* a   = L ? a2   : a1;
    float*       sC  = L ? sC2  : sC1;
    __shared__ float red[256];
    int n = tid >> 1, half = tid & 1;
    float aC = a[256 + n];
    for (int r = 0; r < NR; ++r){
      float p = 0.f;
      for (int k = half * 100; k < half * 100 + 100; ++k)
        p += rel[r * RD + k] * Wr[n * RD + k];
      red[tid] = p * aC;
      __syncthreads();
      for (int s = 128; s > 0; s >>= 1){
        if (tid < s) red[tid] += red[tid + s];
        __syncthreads();
      }
      if (tid == 0) sC[r] = red[0];
      __syncthreads();
    }
  }
}

// ---------------- CSR build ----------------
__global__ void degcount_k(const int* __restrict__ dst, int* __restrict__ deg){
  int e = blockIdx.x * 256 + threadIdx.x;
  if (e < E) atomicAdd(&deg[dst[e]], 1);
}

__global__ void scan1_k(const int* __restrict__ deg, int* __restrict__ chunk,
                        int* __restrict__ bsums, int n){
  __shared__ int s[256];
  int tid = threadIdx.x, i = blockIdx.x * 256 + tid;
  int v = (i < n) ? deg[i] : 0;
  s[tid] = v; __syncthreads();
  for (int off = 1; off < 256; off <<= 1){
    int t = (tid >= off) ? s[tid - off] : 0;
    __syncthreads();
    s[tid] += t;
    __syncthreads();
  }
  if (i < n) chunk[i] = s[tid] - v;
  if (tid == 255) bsums[blockIdx.x] = s[255];
}

__global__ void scan2_k(const int* __restrict__ bsums, int* __restrict__ boffs, int nb){
  __shared__ int s[256];
  int tid = threadIdx.x;
  int v = (tid < nb) ? bsums[tid] : 0;
  s[tid] = v; __syncthreads();
  for (int off = 1; off < 256; off <<= 1){
    int t = (tid >= off) ? s[tid - off] : 0;
    __syncthreads();
    s[tid] += t;
    __syncthreads();
  }
  if (tid < nb) boffs[tid] = s[tid] - v;
}

__global__ void scan3_k(int* __restrict__ rowptr, const int* __restrict__ boffs,
                        int* __restrict__ cursor, int n, int total){
  int i = blockIdx.x * 256 + threadIdx.x;
  if (i < n){
    int v = rowptr[i] + boffs[blockIdx.x];
    rowptr[i] = v; cursor[i] = v;
  }
  if (i == 0) rowptr[n] = total;
}

// fill CSR adjacency with (type<<16)|src packed (src < 65536, type < 8)
__global__ void fill_k(const int* __restrict__ src, const int* __restrict__ dst,
                       const int* __restrict__ et, int* __restrict__ cursor,
                       int* __restrict__ cpk){
  int e = blockIdx.x * 256 + threadIdx.x;
  if (e < E){
    int d = dst[e];
    int p = atomicAdd(&cursor[d], 1);
    cpk[p] = src[e] | (et[e] << 16);
  }
}

// --------- fused double-GEMM: out1 = f1(A @ W1^T), out2 = f2(out1 @ W2^T) ---------
// BARRIER-FREE GEMM1: A-fragments and B-fragments loaded directly from global
// (per-lane dwordx4) -- each A element is consumed by exactly one lane, and B
// fragments are L1/L2-broadcast across waves/blocks, so LDS staging was pure
// overhead (and its 2 barriers/k-iter lock-stepped all resident waves onto the
// HBM latency).  Only the GEMM1->GEMM2 forwarding tile Cs lives in LDS, with a
// T2-style XOR chunk swizzle: phys 16B-chunk = chunk ^ (row & 7)  (conflict-free
// b128 reads, ~2-way scalar writes).  One barrier per kernel.
// M1: 1 = +bias1, leaky(0.01)    2 = elu(acc + agg)   [agg read direct, L2-hot]
// NORM: fused row L2-normalize after f1
// STORE1: write bf16 tile of stage-1 result to out1
// M2: 1 = +vec2 bias, leaky(0.01), fp32 out2    3 = bf16 out2 + sA/sB (vec2 = a)
template<int K1, int M1, bool AFP32, bool NORM, bool STORE1, int M2>
__global__ __launch_bounds__(256, 3) void gfused_k(
    const void* __restrict__ Ap, const ushort_t* __restrict__ Wb1,
    const float* __restrict__ bias1, const ushort_t* __restrict__ aggM,
    ushort_t* __restrict__ out1,
    const ushort_t* __restrict__ Wb2, const float* __restrict__ vec2,
    void* __restrict__ out2, float* __restrict__ sA, float* __restrict__ sB, int M)
{
  __shared__ __align__(16) ushort_t Cs[64 * 128];   // 16 KB, XOR-swizzled chunks
  const int tid  = threadIdx.x;
  const int wave = tid >> 6, lane = tid & 63;
  const int l15  = lane & 15, quad = lane >> 4;
  const int row0 = blockIdx.x * 64;
  const int arow_l = wave * 16 + l15;               // A-fragment row (local)
  int ar = row0 + arow_l; if (ar >= M) ar = M - 1;  // clamp; garbage rows never stored

  f32x4 acc[8];
  #pragma unroll
  for (int t = 0; t < 8; ++t) acc[t] = (f32x4){0.f, 0.f, 0.f, 0.f};

  // ================= GEMM 1: A[M x K1] @ W1^T, no LDS, no barriers =================
  const ushort_t* wb = Wb1 + (size_t)l15 * K1 + quad * 8;
  if (AFP32){
    const float* ap = (const float*)Ap + (size_t)ar * K1 + quad * 8;
    #pragma unroll 2
    for (int k0 = 0; k0 < K1; k0 += 32){
      float4 u0 = *reinterpret_cast<const float4*>(ap + k0);
      float4 u1 = *reinterpret_cast<const float4*>(ap + k0 + 4);
      uint4 av;
      av.x = cvtpk(u0.x, u0.y); av.y = cvtpk(u0.z, u0.w);
      av.z = cvtpk(u1.x, u1.y); av.w = cvtpk(u1.z, u1.w);
      bf16x8 af = __builtin_bit_cast(bf16x8, av);
      #pragma unroll
      for (int t = 0; t < 8; ++t){
        bf16x8 bfr = *reinterpret_cast<const bf16x8*>(wb + (size_t)t * 16 * K1 + k0);
        acc[t] = __builtin_amdgcn_mfma_f32_16x16x32_bf16(af, bfr, acc[t], 0, 0, 0);
      }
    }
  } else {
    const ushort_t* apb = (const ushort_t*)Ap + (size_t)ar * K1 + quad * 8;
    #pragma unroll 2
    for (int k0 = 0; k0 < K1; k0 += 32){
      bf16x8 af = *reinterpret_cast<const bf16x8*>(apb + k0);
      #pragma unroll
      for (int t = 0; t < 8; ++t){
        bf16x8 bfr = *reinterpret_cast<const bf16x8*>(wb + (size_t)t * 16 * K1 + k0);
        acc[t] = __builtin_amdgcn_mfma_f32_16x16x32_bf16(af, bfr, acc[t], 0, 0, 0);
      }
    }
  }

  // ---- epilogue 1: C/D map col=t*16+l15, local row lr0+r = wave*16+quad*4+r ----
  const int lr0 = wave * 16 + quad * 4;
  float vv[8][4];
  #pragma unroll
  for (int t = 0; t < 8; ++t){
    #pragma unroll
    for (int r = 0; r < 4; ++r){
      int col = t * 16 + l15;
      float v = acc[t][r];
      if (M1 == 1){
        v += bias1[col];
        v = v > 0.f ? v : 0.01f * v;
      } else { // M1 == 2: residual from agg matrix, direct (L2/L3-hot) load
        int g = row0 + lr0 + r;
        float ag = (g < M) ? b2f_us(aggM[(size_t)g * 128 + col]) : 0.f;
        v += ag;
        v = v > 0.f ? v : __expf(v) - 1.f;
      }
      vv[t][r] = v;
    }
  }
  if (NORM){
    #pragma unroll
    for (int r = 0; r < 4; ++r){
      float ss = 0.f;
      #pragma unroll
      for (int t = 0; t < 8; ++t) ss += vv[t][r] * vv[t][r];
      #pragma unroll
      for (int off = 1; off < 16; off <<= 1) ss += __shfl_xor(ss, off, 64);
      float sc = 1.f / fmaxf(sqrtf(ss), 1e-12f);
      #pragma unroll
      for (int t = 0; t < 8; ++t) vv[t][r] *= sc;
    }
  }
  // write swizzled Cs tile (+ optional out1)
  #pragma unroll
  for (int t = 0; t < 8; t += 2){
    #pragma unroll
    for (int r = 0; r < 4; ++r){
      int row = lr0 + r;
      int key = row & 7;
      uint_t pr = cvtpk(vv[t][r], vv[t + 1][r]);
      int c0 = t * 16 + l15, c1 = c0 + 16;
      int p0 = ((c0 >> 3) ^ key) << 3, p1 = ((c1 >> 3) ^ key) << 3;
      Cs[row * 128 + p0 + (l15 & 7)] = (ushort_t)pr;
      Cs[row * 128 + p1 + (l15 & 7)] = (ushort_t)(pr >> 16);
      if (STORE1){
        int g = row0 + row;
        if (g < M){
          out1[(size_t)g * 128 + c0] = (ushort_t)pr;
          out1[(size_t)g * 128 + c1] = (ushort_t)(pr >> 16);
        }
      }
    }
  }
  __syncthreads();

  // ============ GEMM 2: Cs[64 x 128] @ W2^T, B direct from global (L2-hot) ============
  #pragma unroll
  for (int t = 0; t < 8; ++t) acc[t] = (f32x4){0.f, 0.f, 0.f, 0.f};
  {
    const int rr   = wave * 16 + l15;      // rr & 7 == l15 & 7
    const int rkey = l15 & 7;
    const ushort_t* w2 = Wb2 + (size_t)l15 * 128 + quad * 8;
    #pragma unroll 2
    for (int kk = 0; kk < 4; ++kk){
      int ph = (((kk * 4 + quad) ^ rkey) << 3);
      bf16x8 af2 = *reinterpret_cast<const bf16x8*>(&Cs[rr * 128 + ph]);
      #pragma unroll
      for (int t = 0; t < 8; ++t){
        bf16x8 bfr = *reinterpret_cast<const bf16x8*>(w2 + (size_t)t * 16 * 128 + kk * 32);
        acc[t] = __builtin_amdgcn_mfma_f32_16x16x32_bf16(af2, bfr, acc[t], 0, 0, 0);
      }
    }
  }

  // ---- epilogue 2 ----
  if (M2 == 1){
    #pragma unroll
    for (int t = 0; t < 8; ++t){
      #pragma unroll
      for (int r = 0; r < 4; ++r){
        int grow = row0 + lr0 + r;
        if (grow >= M) continue;
        int col = t * 16 + l15;
        float v = acc[t][r] + vec2[col];
        v = v > 0.f ? v : 0.01f * v;
        ((float*)out2)[(size_t)grow * 128 + col] = v;
      }
    }
  } else { // M2 == 3: bf16 out + per-row sA/sB
    #pragma unroll
    for (int t = 0; t < 8; t += 2){
      #pragma unroll
      for (int r = 0; r < 4; ++r){
        int grow = row0 + lr0 + r;
        if (grow >= M) continue;
        int c0 = t * 16 + l15;
        uint_t pr = cvtpk(acc[t][r], acc[t + 1][r]);
        ((ushort_t*)out2)[(size_t)grow * 128 + c0]      = (ushort_t)pr;
        ((ushort_t*)out2)[(size_t)grow * 128 + c0 + 16] = (ushort_t)(pr >> 16);
      }
    }
    #pragma unroll
    for (int r = 0; r < 4; ++r){
      float pa = 0.f, pb = 0.f;
      #pragma unroll
      for (int t = 0; t < 8; ++t){
        int col = t * 16 + l15;
        pa += acc[t][r] * vec2[col];
        pb += acc[t][r] * vec2[128 + col];
      }
      #pragma unroll
      for (int off = 1; off < 16; off <<= 1){
        pa += __shfl_xor(pa, off, 64);
        pb += __shfl_xor(pb, off, 64);
      }
      int grow = row0 + lr0 + r;
      if (l15 == r && grow < M){ sA[grow] = pa; sB[grow] = pb; }
    }
  }
}

// ------- per-node softmax + aggregate: 16-lane group per node (4 nodes/wave) -------
__global__ __launch_bounds__(256) void agg_k(
    const ushort_t* __restrict__ Wx, const float* __restrict__ sA,
    const float* __restrict__ sB, const float* __restrict__ sC,
    const int* __restrict__ rowptr, const int* __restrict__ cpk,
    uint_t* __restrict__ aggU, int n)
{
  const int node  = blockIdx.x * 16 + (threadIdx.x >> 4);
  const int l     = threadIdx.x & 15;    // lane in group
  const int gbase = threadIdx.x & 48;    // group base lane within wave
  if (node >= n) return;
  int p0 = rowptr[node], p1 = rowptr[node + 1];
  int deg = p1 - p0;
  float sa = sA[node];
  float m = -1e30f, ssum = 0.f;
  float a[8];
  #pragma unroll
  for (int j = 0; j < 8; ++j) a[j] = 0.f;

  for (int c0 = 0; c0 < deg; c0 += 16){
    int cnt = deg - c0; if (cnt > 16) cnt = 16;
    bool ok = l < cnt;
    int pk = cpk[p0 + c0 + (ok ? l : 0)];
    float s = sa + sB[pk & 0xFFFF] + sC[pk >> 16];
    s = s > 0.f ? s : 0.2f * s;                    // leaky_relu(., 0.2)
    float sv = ok ? s : -1e30f;
    #pragma unroll
    for (int off = 8; off > 0; off >>= 1) sv = fmaxf(sv, __shfl_xor(sv, off, 16));
    float mn = fmaxf(m, sv);
    float corr = __expf(m - mn);
    ssum *= corr;
    #pragma unroll
    for (int j = 0; j < 8; ++j) a[j] *= corr;
    float ev = ok ? __expf(s - mn) : 0.f;          // ev == 0 on masked lanes
    float es = ev;
    #pragma unroll
    for (int off = 8; off > 0; off >>= 1) es += __shfl_xor(es, off, 16);
    ssum += es;
    m = mn;
    int png = ok ? pk : 0;

    for (int e = 0; e < cnt; e += 4){              // tail edges neutralized by ev=0
      int b0l = gbase + e;
      int pe0 = __shfl(png, b0l,     64), pe1 = __shfl(png, b0l + 1, 64);
      int pe2 = __shfl(png, b0l + 2, 64), pe3 = __shfl(png, b0l + 3, 64);
      float e0 = __shfl(ev, b0l,     64), e1 = __shfl(ev, b0l + 1, 64);
      float e2 = __shfl(ev, b0l + 2, 64), e3 = __shfl(ev, b0l + 3, 64);
      uint4 u0 = *reinterpret_cast<const uint4*>(Wx + (size_t)(pe0 & 0xFFFF) * 128 + l * 8);
      uint4 u1 = *reinterpret_cast<const uint4*>(Wx + (size_t)(pe1 & 0xFFFF) * 128 + l * 8);
      uint4 u2 = *reinterpret_cast<const uint4*>(Wx + (size_t)(pe2 & 0xFFFF) * 128 + l * 8);
      uint4 u3 = *reinterpret_cast<const uint4*>(Wx + (size_t)(pe3 & 0xFFFF) * 128 + l * 8);
      a[0] += e0 * b2f_lo(u0.x); a[1] += e0 * b2f_hi(u0.x);
      a[2] += e0 * b2f_lo(u0.y); a[3] += e0 * b2f_hi(u0.y);
      a[4] += e0 * b2f_lo(u0.z); a[5] += e0 * b2f_hi(u0.z);
      a[6] += e0 * b2f_lo(u0.w); a[7] += e0 * b2f_hi(u0.w);
      a[0] += e1 * b2f_lo(u1.x); a[1] += e1 * b2f_hi(u1.x);
      a[2] += e1 * b2f_lo(u1.y); a[3] += e1 * b2f_hi(u1.y);
      a[4] += e1 * b2f_lo(u1.z); a[5] += e1 * b2f_hi(u1.z);
      a[6] += e1 * b2f_lo(u1.w); a[7] += e1 * b2f_hi(u1.w);
      a[0] += e2 * b2f_lo(u2.x); a[1] += e2 * b2f_hi(u2.x);
      a[2] += e2 * b2f_lo(u2.y); a[3] += e2 * b2f_hi(u2.y);
      a[4] += e2 * b2f_lo(u2.z); a[5] += e2 * b2f_hi(u2.z);
      a[6] += e2 * b2f_lo(u2.w); a[7] += e2 * b2f_hi(u2.w);
      a[0] += e3 * b2f_lo(u3.x); a[1] += e3 * b2f_hi(u3.x);
      a[2] += e3 * b2f_lo(u3.y); a[3] += e3 * b2f_hi(u3.y);
      a[4] += e3 * b2f_lo(u3.z); a[5] += e3 * b2f_hi(u3.z);
      a[6] += e3 * b2f_lo(u3.w); a[7] += e3 * b2f_hi(u3.w);
    }
  }
  float inv = (deg > 0) ? 1.f / ssum : 0.f;        // degree-0 -> zero row
  uint4 o;
  o.x = cvtpk(a[0] * inv, a[1] * inv);
  o.y = cvtpk(a[2] * inv, a[3] * inv);
  o.z = cvtpk(a[4] * inv, a[5] * inv);
  o.w = cvtpk(a[6] * inv, a[7] * inv);
  *reinterpret_cast<uint4*>(aggU + (size_t)node * 64 + l * 4) = o;   // cols l*8..l*8+7
}

} // namespace

extern "C" void kernel_launch(void* const* d_in, const int* in_sizes, int n_in,
                              void* d_out, int out_size, void* d_ws, size_t ws_size,
                              hipStream_t stream)
{
  const float* x     = (const float*)d_in[0];
  const int*   eidx  = (const int*)d_in[1];
  const int*   et    = (const int*)d_in[2];
  const float* l1W   = (const float*)d_in[3];
  const float* l1b   = (const float*)d_in[4];
  const float* l2W   = (const float*)d_in[5];
  const float* l2b   = (const float*)d_in[6];
  const float* W1    = (const float*)d_in[7];
  const float* Wr1   = (const float*)d_in[8];
  const float* a1    = (const float*)d_in[9];
  const float* Wres1 = (const float*)d_in[10];
  const float* rel1  = (const float*)d_in[11];
  const float* W2    = (const float*)d_in[12];
  const float* Wr2   = (const float*)d_in[13];
  const float* a2    = (const float*)d_in[14];
  const float* Wres2 = (const float*)d_in[15];
  const float* rel2  = (const float*)d_in[16];
  float* outp = (float*)d_out;

  const int* esrc = eidx;        // edge_index[0]
  const int* edst = eidx + E;    // edge_index[1]

  // -------- workspace layout --------
  float* f = (float*)d_ws;
  size_t o = 0;
  float* sA   = f + o; o += N;
  float* sB   = f + o; o += N;
  float* sC1  = f + o; o += 8;
  float* sC2  = f + o; o += 8;
  ushort_t* us = (ushort_t*)(f + o);
  size_t ou = 0;
  ushort_t* b0   = us + ou; ou += (size_t)N * H;    // h0 bf16
  ushort_t* b1   = us + ou; ou += (size_t)N * H;    // h1 bf16
  ushort_t* Wxb  = us + ou; ou += (size_t)N * H;    // Wx bf16
  ushort_t* aggB = us + ou; ou += (size_t)N * H;    // agg bf16
  ushort_t* wtsb = us + ou; ou += (size_t)H * KIN + 5 * H * H;
  ushort_t* l1Wb = wtsb;
  ushort_t* W1b  = wtsb + H * KIN;
  ushort_t* R1b  = W1b + H * H;
  ushort_t* W2b  = R1b + H * H;
  ushort_t* R2b  = W2b + H * H;
  ushort_t* l2Wb = R2b + H * H;
  if (ou & 1) ou += 1;
  int* wi = (int*)(us + ou);
  size_t oi = 0;
  int* deg    = wi + oi; oi += N;
  int* rowptr = wi + oi; oi += N + 1;
  int* cursor = wi + oi; oi += N;
  int* bsums  = wi + oi; oi += 256;
  int* boffs  = wi + oi; oi += 256;
  int* cpk    = wi + oi; oi += E;

  const int EB    = (E + 255) / 256;
  const int NB256 = (N + 255) / 256;
  const int GB    = (N + 63) / 64;
  const int NB16  = (N + 15) / 16;

  // -------- prep (weight cvt + deg zero + relsc) & CSR build --------
  prep_k<<<902, 256, 0, stream>>>(l1W, W1, Wres1, W2, Wres2, l2W, wtsb, deg,
                                  rel1, Wr1, a1, sC1, rel2, Wr2, a2, sC2);
  degcount_k<<<EB, 256, 0, stream>>>(edst, deg);
  scan1_k<<<NB256, 256, 0, stream>>>(deg, rowptr, bsums, N);
  scan2_k<<<1, 256, 0, stream>>>(bsums, boffs, NB256);
  scan3_k<<<NB256, 256, 0, stream>>>(rowptr, boffs, cursor, N, E);
  fill_k<<<EB, 256, 0, stream>>>(esrc, edst, et, cursor, cpk);

  // -------- G1: h0 = leaky(x@l1W^T+b) -> b0;  Wx1 = h0@W1^T -> Wxb (+sA/sB) --------
  gfused_k<KIN, 1, true, false, true, 3><<<GB, 256, 0, stream>>>(
      x, l1Wb, l1b, nullptr, b0, W1b, a1, Wxb, sA, sB, N);
  agg_k<<<NB16, 256, 0, stream>>>(Wxb, sA, sB, sC1, rowptr, cpk, (uint_t*)aggB, N);

  // -------- G2: h1 = elu(agg1 + b0@R1^T) -> b1;  Wx2 = h1@W2^T -> Wxb (+sA/sB) --------
  gfused_k<H, 2, false, false, true, 3><<<GB, 256, 0, stream>>>(
      b0, R1b, nullptr, aggB, b1, W2b, a2, Wxb, sA, sB, N);
  agg_k<<<NB16, 256, 0, stream>>>(Wxb, sA, sB, sC2, rowptr, cpk, (uint_t*)aggB, N);

  // -------- G3: h2 = normalize(elu(agg2 + b1@R2^T));  out = leaky(h2@l2W^T+b) --------
  gfused_k<H, 2, false, true, false, 1><<<GB, 256, 0, stream>>>(
      b1, R2b, nullptr, aggB, nullptr, l2Wb, l2b, outp, nullptr, nullptr, N);
}

// Round 3
// 524.146 us; speedup vs baseline: 1.0975x; 1.0975x over previous
//
#include <hip/hip_runtime.h>

namespace {

typedef unsigned short ushort_t;
typedef unsigned int uint_t;
typedef __attribute__((ext_vector_type(8))) short bf16x8;
typedef __attribute__((ext_vector_type(4))) float f32x4;

constexpr int N   = 50000;
constexpr int E   = 600000;
constexpr int NR  = 5;
constexpr int KIN = 768;
constexpr int H   = 128;
constexpr int RD  = 200;

__device__ inline ushort_t f2b(float f){           // fp32 -> bf16 bits, RNE
  uint_t u = __builtin_bit_cast(uint_t, f);
  uint_t r = (u + 0x7FFFu + ((u >> 16) & 1u)) >> 16;
  return (ushort_t)r;
}
__device__ inline float b2f_lo(uint_t u){ return __builtin_bit_cast(float, u << 16); }
__device__ inline float b2f_hi(uint_t u){ return __builtin_bit_cast(float, u & 0xFFFF0000u); }
__device__ inline float b2f_us(ushort_t h){ return __builtin_bit_cast(float, ((uint_t)h) << 16); }
__device__ inline uint_t cvtpk(float lo, float hi){ // 2x fp32 -> packed bf16 (RNE), 1 instr
  uint_t r;
  asm("v_cvt_pk_bf16_f32 %0, %1, %2" : "=v"(r) : "v"(lo), "v"(hi));
  return r;
}

typedef __attribute__((address_space(1))) const unsigned int glb_u32;
typedef __attribute__((address_space(3))) unsigned int lds_u32;
__device__ __forceinline__ void glds16(const void* g, void* l){
  __builtin_amdgcn_global_load_lds((glb_u32*)g, (lds_u32*)l, 16, 0, 0);
}
template<int Nn> __device__ __forceinline__ void wait_vmcnt(){
  asm volatile("s_waitcnt vmcnt(%0)" :: "n"(Nn) : "memory");
}
__device__ __forceinline__ void wait_lgkm0(){
  asm volatile("s_waitcnt lgkmcnt(0)" ::: "memory");
}

// ---- prep: weight cvt (blocks 0..703) + zero deg (704..899) + relsc (900..901) ----
__global__ void prep_k(const float* __restrict__ l1W, const float* __restrict__ W1,
                       const float* __restrict__ R1, const float* __restrict__ W2,
                       const float* __restrict__ R2, const float* __restrict__ l2W,
                       ushort_t* __restrict__ wts, int* __restrict__ deg,
                       const float* __restrict__ rel1, const float* __restrict__ Wr1,
                       const float* __restrict__ a1, float* __restrict__ sC1,
                       const float* __restrict__ rel2, const float* __restrict__ Wr2,
                       const float* __restrict__ a2, float* __restrict__ sC2){
  constexpr int S0 = H * KIN;        // 98304
  constexpr int S1 = H * H;          // 16384
  int b = blockIdx.x, tid = threadIdx.x;
  if (b < 704){                      // weight convert: 704*256 == S0 + 5*S1 exactly
    int i = b * 256 + tid;
    float v;
    if (i < S0) v = l1W[i];
    else {
      int j = i - S0, seg = j >> 14, off = j & (S1 - 1);
      const float* srcs[5] = {W1, R1, W2, R2, l2W};
      v = srcs[seg][off];
    }
    wts[i] = f2b(v);
  } else if (b < 900){               // zero deg
    int i = (b - 704) * 256 + tid;
    if (i < N) deg[i] = 0;
  } else {                           // relation scalars, one block per layer
    int L = b - 900;
    const float* rel = L ? rel2 : rel1;
    const float* Wr  = L ? Wr2  : Wr1;
    const float* a   = L ? a2   : a1;
    float*       sC  = L ? sC2  : sC1;
    __shared__ float red[256];
    int n = tid >> 1, half = tid & 1;
    float aC = a[256 + n];
    for (int r = 0; r < NR; ++r){
      float p = 0.f;
      for (int k = half * 100; k < half * 100 + 100; ++k)
        p += rel[r * RD + k] * Wr[n * RD + k];
      red[tid] = p * aC;
      __syncthreads();
      for (int s = 128; s > 0; s >>= 1){
        if (tid < s) red[tid] += red[tid + s];
        __syncthreads();
      }
      if (tid == 0) sC[r] = red[0];
      __syncthreads();
    }
  }
}

// ---------------- CSR build ----------------
__global__ void degcount_k(const int* __restrict__ dst, int* __restrict__ deg){
  int e = blockIdx.x * 256 + threadIdx.x;
  if (e < E) atomicAdd(&deg[dst[e]], 1);
}

__global__ void scan1_k(const int* __restrict__ deg, int* __restrict__ chunk,
                        int* __restrict__ bsums, int n){
  __shared__ int s[256];
  int tid = threadIdx.x, i = blockIdx.x * 256 + tid;
  int v = (i < n) ? deg[i] : 0;
  s[tid] = v; __syncthreads();
  for (int off = 1; off < 256; off <<= 1){
    int t = (tid >= off) ? s[tid - off] : 0;
    __syncthreads();
    s[tid] += t;
    __syncthreads();
  }
  if (i < n) chunk[i] = s[tid] - v;
  if (tid == 255) bsums[blockIdx.x] = s[255];
}

__global__ void scan2_k(const int* __restrict__ bsums, int* __restrict__ boffs, int nb){
  __shared__ int s[256];
  int tid = threadIdx.x;
  int v = (tid < nb) ? bsums[tid] : 0;
  s[tid] = v; __syncthreads();
  for (int off = 1; off < 256; off <<= 1){
    int t = (tid >= off) ? s[tid - off] : 0;
    __syncthreads();
    s[tid] += t;
    __syncthreads();
  }
  if (tid < nb) boffs[tid] = s[tid] - v;
}

__global__ void scan3_k(int* __restrict__ rowptr, const int* __restrict__ boffs,
                        int* __restrict__ cursor, int n, int total){
  int i = blockIdx.x * 256 + threadIdx.x;
  if (i < n){
    int v = rowptr[i] + boffs[blockIdx.x];
    rowptr[i] = v; cursor[i] = v;
  }
  if (i == 0) rowptr[n] = total;
}

// fill CSR adjacency with (type<<16)|src packed (src < 65536, type < 8)
__global__ void fill_k(const int* __restrict__ src, const int* __restrict__ dst,
                       const int* __restrict__ et, int* __restrict__ cursor,
                       int* __restrict__ cpk){
  int e = blockIdx.x * 256 + threadIdx.x;
  if (e < E){
    int d = dst[e];
    int p = atomicAdd(&cursor[d], 1);
    cpk[p] = src[e] | (et[e] << 16);
  }
}

// --------- fused double-GEMM: out1 = f1(A @ W1^T), out2 = f2(out1 @ W2^T) ---------
// GEMM1 is a counted-vmcnt pipeline (T3+T4 minimum): B tiles via async
// global_load_lds into a 3-deep LDS ring; A reg-staged 1 iter ahead into a
// 2-buffer LDS; ONE raw s_barrier per k-iter with s_waitcnt vmcnt(AI+2) at the
// top -- prefetched loads stay in flight ACROSS barriers (never drained to 0).
// Ledger: only VMEM ops newer than B(t)'s glds are A(t+1)+B(t+1) = AI+2 instrs.
// GEMM2: Cs (XOR-chunk-swizzled, conflict-free b128) @ W2 direct from L2-hot global.
// M1: 1 = +bias1, leaky(0.01)    2 = elu(acc + agg)  [agg restaged into dead B-ring]
// NORM: fused row L2-normalize; STORE1: write stage-1 bf16 to out1
// M2: 1 = +vec2 bias, leaky(0.01), fp32 out2    3 = bf16 out2 + sA/sB (vec2 = a)
template<int K1, int M1, bool AFP32, bool NORM, bool STORE1, int M2>
__global__ __launch_bounds__(256, 3) void gfused_k(
    const void* __restrict__ Ap, const ushort_t* __restrict__ Wb1,
    const float* __restrict__ bias1, const ushort_t* __restrict__ aggM,
    ushort_t* __restrict__ out1,
    const ushort_t* __restrict__ Wb2, const float* __restrict__ vec2,
    void* __restrict__ out2, float* __restrict__ sA, float* __restrict__ sB, int M)
{
  constexpr int NT = K1 / 32;             // k-iters (24 or 4), always even
  constexpr int AI = AFP32 ? 2 : 1;       // A-load instrs per thread per iter
  __shared__ __align__(16) ushort_t Abuf[2][64 * 32];    //  8 KB
  __shared__ __align__(16) ushort_t Bbuf[3][128 * 32];   // 24 KB ring
  __shared__ __align__(16) ushort_t Cs[64 * 128];        // 16 KB swizzled
  const int tid  = threadIdx.x;
  const int wave = tid >> 6, lane = tid & 63;
  const int l15  = lane & 15, quad = lane >> 4;
  const int row0 = blockIdx.x * 64;

  // A staging: thread covers row tid>>2, k-seg (tid&3)*8 (16B bf16 / 32B fp32)
  int arow_ld = row0 + (tid >> 2); if (arow_ld >= M) arow_ld = M - 1;
  const int aoff  = (tid & 3) * 8;
  const int awoff = (tid >> 2) * 32 + aoff;
  // B staging: wave w fills ring chunks 2w, 2w+1 (rows 32w..32w+31)
  const int c0 = wave * 2, c1 = wave * 2 + 1;
  const ushort_t* bsrc0 = Wb1 + (size_t)(c0 * 16 + (lane >> 2)) * K1 + (lane & 3) * 8;
  const ushort_t* bsrc1 = bsrc0 + (size_t)16 * K1;

#define ISSUE_A(d0, d1, kk) do{                                               \
    if constexpr (AFP32){                                                     \
      const float* ap_ = (const float*)Ap + (size_t)arow_ld * K1 + (kk) + aoff; \
      d0 = *reinterpret_cast<const uint4*>(ap_);                              \
      d1 = *reinterpret_cast<const uint4*>(ap_ + 4);                          \
    } else {                                                                  \
      d0 = *reinterpret_cast<const uint4*>(                                   \
          (const ushort_t*)Ap + (size_t)arow_ld * K1 + (kk) + aoff);          \
    } }while(0)

#define WRITE_A(bi, s0, s1) do{ uint4 av_;                                    \
    if constexpr (AFP32){                                                     \
      float4 f0_ = __builtin_bit_cast(float4, s0);                            \
      float4 f1_ = __builtin_bit_cast(float4, s1);                            \
      av_.x = cvtpk(f0_.x, f0_.y); av_.y = cvtpk(f0_.z, f0_.w);               \
      av_.z = cvtpk(f1_.x, f1_.y); av_.w = cvtpk(f1_.z, f1_.w);               \
    } else av_ = s0;                                                          \
    *reinterpret_cast<uint4*>(&Abuf[bi][awoff]) = av_; }while(0)

#define ISSUE_B(bi, kk) do{                                                   \
    glds16(bsrc0 + (kk), &Bbuf[bi][c0 * 512]);                                \
    glds16(bsrc1 + (kk), &Bbuf[bi][c1 * 512]); }while(0)

#define KSTEP(ab, bb) do{                                                     \
    bf16x8 af_ = *reinterpret_cast<const bf16x8*>(                            \
        &Abuf[ab][(wave * 16 + l15) * 32 + quad * 8]);                        \
    _Pragma("unroll")                                                         \
    for (int t_ = 0; t_ < 8; ++t_){                                           \
      bf16x8 bf_ = *reinterpret_cast<const bf16x8*>(                          \
          &Bbuf[bb][(t_ * 16 + l15) * 32 + quad * 8]);                        \
      acc[t_] = __builtin_amdgcn_mfma_f32_16x16x32_bf16(af_, bf_, acc[t_], 0, 0, 0); \
    } }while(0)

  f32x4 acc[8];
  #pragma unroll
  for (int t = 0; t < 8; ++t) acc[t] = (f32x4){0.f, 0.f, 0.f, 0.f};

  // ---- prologue: stage iters 0,1 ----
  uint4 pa0_0, pa0_1, pa1_0, pa1_1;
  ISSUE_A(pa0_0, pa0_1, 0);
  ISSUE_B(0, 0);
  ISSUE_A(pa1_0, pa1_1, 32);
  ISSUE_B(1, 32);
  wait_vmcnt<AI + 4>();                 // A(0) landed (compiler also guards)
  WRITE_A(0, pa0_0, pa0_1);
  wait_lgkm0();
  __builtin_amdgcn_s_barrier();

  // ---- main loop: 1 raw barrier per iter, counted vmcnt, loads 2-deep ----
  int bt = 0;
  for (int t = 0; t < NT; t += 2){
    // even sub-iter t: read Abuf[0]/Bbuf[bt]; cvt A(t+1)->Abuf[1]; issue t+2
    wait_vmcnt<AI + 2>();               // B(t) complete; A/B(t+1) still in flight
    KSTEP(0, bt);
    wait_vmcnt<2>();                    // A(t+1) regs landed
    WRITE_A(1, pa1_0, pa1_1);
    { int b2 = bt + 2; if (b2 >= 3) b2 -= 3;
      if (t + 2 < NT){ ISSUE_A(pa0_0, pa0_1, (t + 2) * 32); ISSUE_B(b2, (t + 2) * 32); } }
    wait_lgkm0();
    __builtin_amdgcn_s_barrier();
    bt = (bt >= 2) ? 0 : bt + 1;
    // odd sub-iter t+1: read Abuf[1]/Bbuf[bt]; cvt A(t+2)->Abuf[0]; issue t+3
    wait_vmcnt<AI + 2>();
    KSTEP(1, bt);
    if (t + 2 < NT){
      wait_vmcnt<2>();
      WRITE_A(0, pa0_0, pa0_1);
    }
    { int b2 = bt + 2; if (b2 >= 3) b2 -= 3;
      if (t + 3 < NT){ ISSUE_A(pa1_0, pa1_1, (t + 3) * 32); ISSUE_B(b2, (t + 3) * 32); } }
    wait_lgkm0();
    __builtin_amdgcn_s_barrier();
    bt = (bt >= 2) ? 0 : bt + 1;
  }
#undef ISSUE_A
#undef WRITE_A
#undef ISSUE_B
#undef KSTEP

  // ---- M1==2: restage agg tile coalesced into the (now dead) B ring ----
  ushort_t* Ag = &Bbuf[0][0];           // 16 KB spans Bbuf[0..1]
  if (M1 == 2){
    #pragma unroll
    for (int i = 0; i < 4; ++i){
      int idx = tid + 256 * i, r = idx >> 4, c8 = idx & 15;
      int g = row0 + r;
      uint4 v = make_uint4(0, 0, 0, 0);
      if (g < M) v = *reinterpret_cast<const uint4*>(aggM + (size_t)g * 128 + c8 * 8);
      *reinterpret_cast<uint4*>(&Ag[r * 128 + c8 * 8]) = v;
    }
    __syncthreads();
  }

  // ---- epilogue 1: C/D map col=t*16+l15, local row lr0+r = wave*16+quad*4+r ----
  const int lr0 = wave * 16 + quad * 4;
  float vv[8][4];
  #pragma unroll
  for (int t = 0; t < 8; ++t){
    #pragma unroll
    for (int r = 0; r < 4; ++r){
      int col = t * 16 + l15;
      float v = acc[t][r];
      if (M1 == 1){
        v += bias1[col];
        v = v > 0.f ? v : 0.01f * v;
      } else { // M1 == 2
        v += b2f_us(Ag[(lr0 + r) * 128 + col]);
        v = v > 0.f ? v : __expf(v) - 1.f;
      }
      vv[t][r] = v;
    }
  }
  if (NORM){
    #pragma unroll
    for (int r = 0; r < 4; ++r){
      float ss = 0.f;
      #pragma unroll
      for (int t = 0; t < 8; ++t) ss += vv[t][r] * vv[t][r];
      #pragma unroll
      for (int off = 1; off < 16; off <<= 1) ss += __shfl_xor(ss, off, 64);
      float sc = 1.f / fmaxf(sqrtf(ss), 1e-12f);
      #pragma unroll
      for (int t = 0; t < 8; ++t) vv[t][r] *= sc;
    }
  }
  // write swizzled Cs tile (+ optional out1)
  #pragma unroll
  for (int t = 0; t < 8; t += 2){
    #pragma unroll
    for (int r = 0; r < 4; ++r){
      int row = lr0 + r;
      int key = row & 7;
      uint_t pr = cvtpk(vv[t][r], vv[t + 1][r]);
      int c0s = t * 16 + l15, c1s = c0s + 16;
      int p0 = ((c0s >> 3) ^ key) << 3, p1 = ((c1s >> 3) ^ key) << 3;
      Cs[row * 128 + p0 + (l15 & 7)] = (ushort_t)pr;
      Cs[row * 128 + p1 + (l15 & 7)] = (ushort_t)(pr >> 16);
      if (STORE1){
        int g = row0 + row;
        if (g < M){
          out1[(size_t)g * 128 + c0s] = (ushort_t)pr;
          out1[(size_t)g * 128 + c1s] = (ushort_t)(pr >> 16);
        }
      }
    }
  }
  __syncthreads();

  // ============ GEMM 2: Cs[64 x 128] @ W2^T, B direct from global (L2-hot) ============
  #pragma unroll
  for (int t = 0; t < 8; ++t) acc[t] = (f32x4){0.f, 0.f, 0.f, 0.f};
  {
    const int rr   = wave * 16 + l15;      // rr & 7 == l15 & 7
    const int rkey = l15 & 7;
    const ushort_t* w2 = Wb2 + (size_t)l15 * 128 + quad * 8;
    #pragma unroll 2
    for (int kk = 0; kk < 4; ++kk){
      int ph = (((kk * 4 + quad) ^ rkey) << 3);
      bf16x8 af2 = *reinterpret_cast<const bf16x8*>(&Cs[rr * 128 + ph]);
      #pragma unroll
      for (int t = 0; t < 8; ++t){
        bf16x8 bfr = *reinterpret_cast<const bf16x8*>(w2 + (size_t)t * 16 * 128 + kk * 32);
        acc[t] = __builtin_amdgcn_mfma_f32_16x16x32_bf16(af2, bfr, acc[t], 0, 0, 0);
      }
    }
  }

  // ---- epilogue 2 ----
  if (M2 == 1){
    #pragma unroll
    for (int t = 0; t < 8; ++t){
      #pragma unroll
      for (int r = 0; r < 4; ++r){
        int grow = row0 + lr0 + r;
        if (grow >= M) continue;
        int col = t * 16 + l15;
        float v = acc[t][r] + vec2[col];
        v = v > 0.f ? v : 0.01f * v;
        ((float*)out2)[(size_t)grow * 128 + col] = v;
      }
    }
  } else { // M2 == 3: bf16 out + per-row sA/sB
    #pragma unroll
    for (int t = 0; t < 8; t += 2){
      #pragma unroll
      for (int r = 0; r < 4; ++r){
        int grow = row0 + lr0 + r;
        if (grow >= M) continue;
        int c0s = t * 16 + l15;
        uint_t pr = cvtpk(acc[t][r], acc[t + 1][r]);
        ((ushort_t*)out2)[(size_t)grow * 128 + c0s]      = (ushort_t)pr;
        ((ushort_t*)out2)[(size_t)grow * 128 + c0s + 16] = (ushort_t)(pr >> 16);
      }
    }
    #pragma unroll
    for (int r = 0; r < 4; ++r){
      float pa = 0.f, pb = 0.f;
      #pragma unroll
      for (int t = 0; t < 8; ++t){
        int col = t * 16 + l15;
        pa += acc[t][r] * vec2[col];
        pb += acc[t][r] * vec2[128 + col];
      }
      #pragma unroll
      for (int off = 1; off < 16; off <<= 1){
        pa += __shfl_xor(pa, off, 64);
        pb += __shfl_xor(pb, off, 64);
      }
      int grow = row0 + lr0 + r;
      if (l15 == r && grow < M){ sA[grow] = pa; sB[grow] = pb; }
    }
  }
}

// ------- per-node softmax + aggregate: 16-lane group per node (4 nodes/wave) -------
__global__ __launch_bounds__(256) void agg_k(
    const ushort_t* __restrict__ Wx, const float* __restrict__ sA,
    const float* __restrict__ sB, const float* __restrict__ sC,
    const int* __restrict__ rowptr, const int* __restrict__ cpk,
    uint_t* __restrict__ aggU, int n)
{
  const int node  = blockIdx.x * 16 + (threadIdx.x >> 4);
  const int l     = threadIdx.x & 15;    // lane in group
  const int gbase = threadIdx.x & 48;    // group base lane within wave
  if (node >= n) return;
  int p0 = rowptr[node], p1 = rowptr[node + 1];
  int deg = p1 - p0;
  float sa = sA[node];
  float m = -1e30f, ssum = 0.f;
  float a[8];
  #pragma unroll
  for (int j = 0; j < 8; ++j) a[j] = 0.f;

  for (int c0 = 0; c0 < deg; c0 += 16){
    int cnt = deg - c0; if (cnt > 16) cnt = 16;
    bool ok = l < cnt;
    int pk = cpk[p0 + c0 + (ok ? l : 0)];
    float s = sa + sB[pk & 0xFFFF] + sC[pk >> 16];
    s = s > 0.f ? s : 0.2f * s;                    // leaky_relu(., 0.2)
    float sv = ok ? s : -1e30f;
    #pragma unroll
    for (int off = 8; off > 0; off >>= 1) sv = fmaxf(sv, __shfl_xor(sv, off, 16));
    float mn = fmaxf(m, sv);
    float corr = __expf(m - mn);
    ssum *= corr;
    #pragma unroll
    for (int j = 0; j < 8; ++j) a[j] *= corr;
    float ev = ok ? __expf(s - mn) : 0.f;          // ev == 0 on masked lanes
    float es = ev;
    #pragma unroll
    for (int off = 8; off > 0; off >>= 1) es += __shfl_xor(es, off, 16);
    ssum += es;
    m = mn;
    int png = ok ? pk : 0;

    for (int e = 0; e < cnt; e += 4){              // tail edges neutralized by ev=0
      int b0l = gbase + e;
      int pe0 = __shfl(png, b0l,     64), pe1 = __shfl(png, b0l + 1, 64);
      int pe2 = __shfl(png, b0l + 2, 64), pe3 = __shfl(png, b0l + 3, 64);
      float e0 = __shfl(ev, b0l,     64), e1 = __shfl(ev, b0l + 1, 64);
      float e2 = __shfl(ev, b0l + 2, 64), e3 = __shfl(ev, b0l + 3, 64);
      uint4 u0 = *reinterpret_cast<const uint4*>(Wx + (size_t)(pe0 & 0xFFFF) * 128 + l * 8);
      uint4 u1 = *reinterpret_cast<const uint4*>(Wx + (size_t)(pe1 & 0xFFFF) * 128 + l * 8);
      uint4 u2 = *reinterpret_cast<const uint4*>(Wx + (size_t)(pe2 & 0xFFFF) * 128 + l * 8);
      uint4 u3 = *reinterpret_cast<const uint4*>(Wx + (size_t)(pe3 & 0xFFFF) * 128 + l * 8);
      a[0] += e0 * b2f_lo(u0.x); a[1] += e0 * b2f_hi(u0.x);
      a[2] += e0 * b2f_lo(u0.y); a[3] += e0 * b2f_hi(u0.y);
      a[4] += e0 * b2f_lo(u0.z); a[5] += e0 * b2f_hi(u0.z);
      a[6] += e0 * b2f_lo(u0.w); a[7] += e0 * b2f_hi(u0.w);
      a[0] += e1 * b2f_lo(u1.x); a[1] += e1 * b2f_hi(u1.x);
      a[2] += e1 * b2f_lo(u1.y); a[3] += e1 * b2f_hi(u1.y);
      a[4] += e1 * b2f_lo(u1.z); a[5] += e1 * b2f_hi(u1.z);
      a[6] += e1 * b2f_lo(u1.w); a[7] += e1 * b2f_hi(u1.w);
      a[0] += e2 * b2f_lo(u2.x); a[1] += e2 * b2f_hi(u2.x);
      a[2] += e2 * b2f_lo(u2.y); a[3] += e2 * b2f_hi(u2.y);
      a[4] += e2 * b2f_lo(u2.z); a[5] += e2 * b2f_hi(u2.z);
      a[6] += e2 * b2f_lo(u2.w); a[7] += e2 * b2f_hi(u2.w);
      a[0] += e3 * b2f_lo(u3.x); a[1] += e3 * b2f_hi(u3.x);
      a[2] += e3 * b2f_lo(u3.y); a[3] += e3 * b2f_hi(u3.y);
      a[4] += e3 * b2f_lo(u3.z); a[5] += e3 * b2f_hi(u3.z);
      a[6] += e3 * b2f_lo(u3.w); a[7] += e3 * b2f_hi(u3.w);
    }
  }
  float inv = (deg > 0) ? 1.f / ssum : 0.f;        // degree-0 -> zero row
  uint4 o;
  o.x = cvtpk(a[0] * inv, a[1] * inv);
  o.y = cvtpk(a[2] * inv, a[3] * inv);
  o.z = cvtpk(a[4] * inv, a[5] * inv);
  o.w = cvtpk(a[6] * inv, a[7] * inv);
  *reinterpret_cast<uint4*>(aggU + (size_t)node * 64 + l * 4) = o;   // cols l*8..l*8+7
}

} // namespace

extern "C" void kernel_launch(void* const* d_in, const int* in_sizes, int n_in,
                              void* d_out, int out_size, void* d_ws, size_t ws_size,
                              hipStream_t stream)
{
  const float* x     = (const float*)d_in[0];
  const int*   eidx  = (const int*)d_in[1];
  const int*   et    = (const int*)d_in[2];
  const float* l1W   = (const float*)d_in[3];
  const float* l1b   = (const float*)d_in[4];
  const float* l2W   = (const float*)d_in[5];
  const float* l2b   = (const float*)d_in[6];
  const float* W1    = (const float*)d_in[7];
  const float* Wr1   = (const float*)d_in[8];
  const float* a1    = (const float*)d_in[9];
  const float* Wres1 = (const float*)d_in[10];
  const float* rel1  = (const float*)d_in[11];
  const float* W2    = (const float*)d_in[12];
  const float* Wr2   = (const float*)d_in[13];
  const float* a2    = (const float*)d_in[14];
  const float* Wres2 = (const float*)d_in[15];
  const float* rel2  = (const float*)d_in[16];
  float* outp = (float*)d_out;

  const int* esrc = eidx;        // edge_index[0]
  const int* edst = eidx + E;    // edge_index[1]

  // -------- workspace layout --------
  float* f = (float*)d_ws;
  size_t o = 0;
  float* sA   = f + o; o += N;
  float* sB   = f + o; o += N;
  float* sC1  = f + o; o += 8;
  float* sC2  = f + o; o += 8;
  ushort_t* us = (ushort_t*)(f + o);
  size_t ou = 0;
  ushort_t* b0   = us + ou; ou += (size_t)N * H;    // h0 bf16
  ushort_t* b1   = us + ou; ou += (size_t)N * H;    // h1 bf16
  ushort_t* Wxb  = us + ou; ou += (size_t)N * H;    // Wx bf16
  ushort_t* aggB = us + ou; ou += (size_t)N * H;    // agg bf16
  ushort_t* wtsb = us + ou; ou += (size_t)H * KIN + 5 * H * H;
  ushort_t* l1Wb = wtsb;
  ushort_t* W1b  = wtsb + H * KIN;
  ushort_t* R1b  = W1b + H * H;
  ushort_t* W2b  = R1b + H * H;
  ushort_t* R2b  = W2b + H * H;
  ushort_t* l2Wb = R2b + H * H;
  if (ou & 1) ou += 1;
  int* wi = (int*)(us + ou);
  size_t oi = 0;
  int* deg    = wi + oi; oi += N;
  int* rowptr = wi + oi; oi += N + 1;
  int* cursor = wi + oi; oi += N;
  int* bsums  = wi + oi; oi += 256;
  int* boffs  = wi + oi; oi += 256;
  int* cpk    = wi + oi; oi += E;

  const int EB    = (E + 255) / 256;
  const int NB256 = (N + 255) / 256;
  const int GB    = (N + 63) / 64;
  const int NB16  = (N + 15) / 16;

  // -------- prep (weight cvt + deg zero + relsc) & CSR build --------
  prep_k<<<902, 256, 0, stream>>>(l1W, W1, Wres1, W2, Wres2, l2W, wtsb, deg,
                                  rel1, Wr1, a1, sC1, rel2, Wr2, a2, sC2);
  degcount_k<<<EB, 256, 0, stream>>>(edst, deg);
  scan1_k<<<NB256, 256, 0, stream>>>(deg, rowptr, bsums, N);
  scan2_k<<<1, 256, 0, stream>>>(bsums, boffs, NB256);
  scan3_k<<<NB256, 256, 0, stream>>>(rowptr, boffs, cursor, N, E);
  fill_k<<<EB, 256, 0, stream>>>(esrc, edst, et, cursor, cpk);

  // -------- G1: h0 = leaky(x@l1W^T+b) -> b0;  Wx1 = h0@W1^T -> Wxb (+sA/sB) --------
  gfused_k<KIN, 1, true, false, true, 3><<<GB, 256, 0, stream>>>(
      x, l1Wb, l1b, nullptr, b0, W1b, a1, Wxb, sA, sB, N);
  agg_k<<<NB16, 256, 0, stream>>>(Wxb, sA, sB, sC1, rowptr, cpk, (uint_t*)aggB, N);

  // -------- G2: h1 = elu(agg1 + b0@R1^T) -> b1;  Wx2 = h1@W2^T -> Wxb (+sA/sB) --------
  gfused_k<H, 2, false, false, true, 3><<<GB, 256, 0, stream>>>(
      b0, R1b, nullptr, aggB, b1, W2b, a2, Wxb, sA, sB, N);
  agg_k<<<NB16, 256, 0, stream>>>(Wxb, sA, sB, sC2, rowptr, cpk, (uint_t*)aggB, N);

  // -------- G3: h2 = normalize(elu(agg2 + b1@R2^T));  out = leaky(h2@l2W^T+b) --------
  gfused_k<H, 2, false, true, false, 1><<<GB, 256, 0, stream>>>(
      b1, R2b, nullptr, aggB, nullptr, l2Wb, l2b, outp, nullptr, nullptr, N);
}

// Round 4
// 516.084 us; speedup vs baseline: 1.1146x; 1.0156x over previous
//
#include <hip/hip_runtime.h>

namespace {

typedef unsigned short ushort_t;
typedef unsigned int uint_t;
typedef __attribute__((ext_vector_type(8))) short bf16x8;
typedef __attribute__((ext_vector_type(4))) float f32x4;

constexpr int N   = 50000;
constexpr int E   = 600000;
constexpr int NR  = 5;
constexpr int KIN = 768;
constexpr int H   = 128;
constexpr int RD  = 200;

__device__ inline ushort_t f2b(float f){           // fp32 -> bf16 bits, RNE
  uint_t u = __builtin_bit_cast(uint_t, f);
  uint_t r = (u + 0x7FFFu + ((u >> 16) & 1u)) >> 16;
  return (ushort_t)r;
}
__device__ inline float b2f_lo(uint_t u){ return __builtin_bit_cast(float, u << 16); }
__device__ inline float b2f_hi(uint_t u){ return __builtin_bit_cast(float, u & 0xFFFF0000u); }
__device__ inline float b2f_us(ushort_t h){ return __builtin_bit_cast(float, ((uint_t)h) << 16); }
__device__ inline uint_t cvtpk(float lo, float hi){ // 2x fp32 -> packed bf16 (RNE), 1 instr
  uint_t r;
  asm("v_cvt_pk_bf16_f32 %0, %1, %2" : "=v"(r) : "v"(lo), "v"(hi));
  return r;
}

// ---- prep: weight cvt (blocks 0..703) + zero deg (704..899) + relsc (900..901) ----
__global__ void prep_k(const float* __restrict__ l1W, const float* __restrict__ W1,
                       const float* __restrict__ R1, const float* __restrict__ W2,
                       const float* __restrict__ R2, const float* __restrict__ l2W,
                       ushort_t* __restrict__ wts, int* __restrict__ deg,
                       const float* __restrict__ rel1, const float* __restrict__ Wr1,
                       const float* __restrict__ a1, float* __restrict__ sC1,
                       const float* __restrict__ rel2, const float* __restrict__ Wr2,
                       const float* __restrict__ a2, float* __restrict__ sC2){
  constexpr int S0 = H * KIN;        // 98304
  constexpr int S1 = H * H;          // 16384
  int b = blockIdx.x, tid = threadIdx.x;
  if (b < 704){                      // weight convert: 704*256 == S0 + 5*S1 exactly
    int i = b * 256 + tid;
    float v;
    if (i < S0) v = l1W[i];
    else {
      int j = i - S0, seg = j >> 14, off = j & (S1 - 1);
      const float* srcs[5] = {W1, R1, W2, R2, l2W};
      v = srcs[seg][off];
    }
    wts[i] = f2b(v);
  } else if (b < 900){               // zero deg
    int i = (b - 704) * 256 + tid;
    if (i < N) deg[i] = 0;
  } else {                           // relation scalars, one block per layer
    int L = b - 900;
    const float* rel = L ? rel2 : rel1;
    const float* Wr  = L ? Wr2  : Wr1;
    const float* a   = L ? a2   : a1;
    float*       sC  = L ? sC2  : sC1;
    __shared__ float red[256];
    int n = tid >> 1, half = tid & 1;
    float aC = a[256 + n];
    for (int r = 0; r < NR; ++r){
      float p = 0.f;
      for (int k = half * 100; k < half * 100 + 100; ++k)
        p += rel[r * RD + k] * Wr[n * RD + k];
      red[tid] = p * aC;
      __syncthreads();
      for (int s = 128; s > 0; s >>= 1){
        if (tid < s) red[tid] += red[tid + s];
        __syncthreads();
      }
      if (tid == 0) sC[r] = red[0];
      __syncthreads();
    }
  }
}

// ---------------- CSR build ----------------
__global__ void degcount_k(const int* __restrict__ dst, int* __restrict__ deg){
  int e = blockIdx.x * 256 + threadIdx.x;
  if (e < E) atomicAdd(&deg[dst[e]], 1);
}

__global__ void scan1_k(const int* __restrict__ deg, int* __restrict__ chunk,
                        int* __restrict__ bsums, int n){
  __shared__ int s[256];
  int tid = threadIdx.x, i = blockIdx.x * 256 + tid;
  int v = (i < n) ? deg[i] : 0;
  s[tid] = v; __syncthreads();
  for (int off = 1; off < 256; off <<= 1){
    int t = (tid >= off) ? s[tid - off] : 0;
    __syncthreads();
    s[tid] += t;
    __syncthreads();
  }
  if (i < n) chunk[i] = s[tid] - v;
  if (tid == 255) bsums[blockIdx.x] = s[255];
}

__global__ void scan2_k(const int* __restrict__ bsums, int* __restrict__ boffs, int nb){
  __shared__ int s[256];
  int tid = threadIdx.x;
  int v = (tid < nb) ? bsums[tid] : 0;
  s[tid] = v; __syncthreads();
  for (int off = 1; off < 256; off <<= 1){
    int t = (tid >= off) ? s[tid - off] : 0;
    __syncthreads();
    s[tid] += t;
    __syncthreads();
  }
  if (tid < nb) boffs[tid] = s[tid] - v;
}

__global__ void scan3_k(int* __restrict__ rowptr, const int* __restrict__ boffs,
                        int* __restrict__ cursor, int n, int total){
  int i = blockIdx.x * 256 + threadIdx.x;
  if (i < n){
    int v = rowptr[i] + boffs[blockIdx.x];
    rowptr[i] = v; cursor[i] = v;
  }
  if (i == 0) rowptr[n] = total;
}

// fill CSR adjacency with (type<<16)|src packed (src < 65536, type < 8)
__global__ void fill_k(const int* __restrict__ src, const int* __restrict__ dst,
                       const int* __restrict__ et, int* __restrict__ cursor,
                       int* __restrict__ cpk){
  int e = blockIdx.x * 256 + threadIdx.x;
  if (e < E){
    int d = dst[e];
    int p = atomicAdd(&cursor[d], 1);
    cpk[p] = src[e] | (et[e] << 16);
  }
}

// --------- fused double-GEMM: out1 = f1(A @ W1^T), out2 = f2(out1 @ W2^T) ---------
// 32-row x 128-col tile, 4 waves; wave w owns 16x64 quadrant (wr=w>>1, wc=w&1).
// Grid = 1563 blocks -> ~6 blocks/CU, 24 waves/CU: doubles per-CU outstanding
// loads vs the 64-row tile (the occupancy-limited bottleneck seen in rounds 1-3).
// Round-1-proven loop: stage->barrier->(prefetch next into regs)->MFMA->barrier.
// Cross-wave-pair (wc=0/1) combines for NORM and sA/sB go through a 512B LDS buf.
// M1: 1 = +bias1, leaky(0.01)    2 = elu(acc + agg)   [agg staged in Cs]
// NORM: fused row L2-normalize after f1
// STORE1: write bf16 tile of stage-1 result to out1
// M2: 1 = +vec2 bias, leaky(0.01), fp32 out2    3 = bf16 out2 + sA/sB (vec2 = a)
template<int K1, int M1, bool AFP32, bool NORM, bool STORE1, int M2>
__global__ __launch_bounds__(256, 6) void gfused_k(
    const void* __restrict__ Ap, const ushort_t* __restrict__ Wb1,
    const float* __restrict__ bias1, const ushort_t* __restrict__ aggM,
    ushort_t* __restrict__ out1,
    const ushort_t* __restrict__ Wb2, const float* __restrict__ vec2,
    void* __restrict__ out2, float* __restrict__ sA, float* __restrict__ sB, int M)
{
  constexpr int AP = 40;   // A k-tile stride (bf16 elems), 80B rows
  constexpr int BP = 40;   // B k-tile stride
  constexpr int CP = 136;  // stage-1 result tile stride; 272B rows, 16B aligned
  __shared__ __align__(16) ushort_t As[32 * AP];    //  2.5 KB
  __shared__ __align__(16) ushort_t Bs[128 * BP];   // 10 KB
  __shared__ __align__(16) ushort_t Cs[32 * CP];    //  8.5 KB
  __shared__ float cmb[2][32][2];                   //  0.5 KB cross-wave combine
  const int tid  = threadIdx.x;
  const int wave = tid >> 6, lane = tid & 63;
  const int l15  = lane & 15, quad = lane >> 4;
  const int wr   = wave >> 1, wc = wave & 1;
  const int row0 = blockIdx.x * 32;

  // ---- stage agg tile into Cs (coalesced); covered by first k-loop barriers ----
  if (M1 == 2){
    #pragma unroll
    for (int i = 0; i < 2; ++i){
      int idx = tid + 256 * i;               // 512 chunks of 8 bf16
      int r = idx >> 4, c8 = idx & 15;
      int g = row0 + r;
      uint4 v = make_uint4(0, 0, 0, 0);
      if (g < M) v = *reinterpret_cast<const uint4*>(aggM + (size_t)g * 128 + c8 * 8);
      *reinterpret_cast<uint4*>(&Cs[r * CP + c8 * 8]) = v;
    }
  }

  f32x4 acc[4];
  #pragma unroll
  for (int t = 0; t < 4; ++t) acc[t] = (f32x4){0.f, 0.f, 0.f, 0.f};

  // ================= GEMM 1: A[M x K1] @ W1^T =================
  // A stage: thread covers row tid>>3 (0..31), k-subseg tid&7 (4 elems)
  const int arow_s = tid >> 3, aseg = tid & 7;
  int agrow = row0 + arow_s; if (agrow >= M) agrow = M - 1;   // clamped load
  const int awoff = arow_s * AP + aseg * 4;
  // B stage: thread covers n-row tid>>1, k-half (tid&1)*16
  const int bn = tid >> 1, bs16 = (tid & 1) * 16;
  const ushort_t* bsrc = Wb1 + (size_t)bn * K1 + bs16;

  float4 pfa; uint2 pua; uint4 pb0, pb1;
  if (AFP32) pfa = *reinterpret_cast<const float4*>((const float*)Ap + (size_t)agrow * K1 + aseg * 4);
  else       pua = *reinterpret_cast<const uint2*>((const ushort_t*)Ap + (size_t)agrow * K1 + aseg * 4);
  pb0 = *reinterpret_cast<const uint4*>(bsrc);
  pb1 = *reinterpret_cast<const uint4*>(bsrc + 8);

  for (int k0 = 0; k0 < K1; k0 += 32){
    { uint2 w;
      if (AFP32){ w.x = cvtpk(pfa.x, pfa.y); w.y = cvtpk(pfa.z, pfa.w); }
      else w = pua;
      *reinterpret_cast<uint2*>(&As[awoff]) = w;
      *reinterpret_cast<uint4*>(&Bs[bn * BP + bs16])     = pb0;
      *reinterpret_cast<uint4*>(&Bs[bn * BP + bs16 + 8]) = pb1;
    }
    __syncthreads();
    if (k0 + 32 < K1){               // prefetch next tile; overlaps MFMAs below
      const int k1 = k0 + 32;
      if (AFP32) pfa = *reinterpret_cast<const float4*>((const float*)Ap + (size_t)agrow * K1 + k1 + aseg * 4);
      else       pua = *reinterpret_cast<const uint2*>((const ushort_t*)Ap + (size_t)agrow * K1 + k1 + aseg * 4);
      pb0 = *reinterpret_cast<const uint4*>(bsrc + k1);
      pb1 = *reinterpret_cast<const uint4*>(bsrc + k1 + 8);
    }
    bf16x8 af = *reinterpret_cast<const bf16x8*>(&As[(wr * 16 + l15) * AP + quad * 8]);
    #pragma unroll
    for (int t = 0; t < 4; ++t){
      bf16x8 bfr = *reinterpret_cast<const bf16x8*>(&Bs[(wc * 64 + t * 16 + l15) * BP + quad * 8]);
      acc[t] = __builtin_amdgcn_mfma_f32_16x16x32_bf16(af, bfr, acc[t], 0, 0, 0);
    }
    __syncthreads();
  }

  // ---- epilogue 1: C/D map col=wc*64+t*16+l15, local row lr0+r = wr*16+quad*4+r ----
  const int lr0 = wr * 16 + quad * 4;
  float vv[4][4];
  #pragma unroll
  for (int t = 0; t < 4; ++t){
    #pragma unroll
    for (int r = 0; r < 4; ++r){
      int col = wc * 64 + t * 16 + l15;
      float v = acc[t][r];
      if (M1 == 1){
        v += bias1[col];
        v = v > 0.f ? v : 0.01f * v;
      } else { // M1 == 2
        v += b2f_us(Cs[(lr0 + r) * CP + col]);   // same cell this thread rewrites below
        v = v > 0.f ? v : __expf(v) - 1.f;
      }
      vv[t][r] = v;
    }
  }
  if (NORM){   // row L2-norm needs both col-halves: combine via LDS
    #pragma unroll
    for (int r = 0; r < 4; ++r){
      float ss = 0.f;
      #pragma unroll
      for (int t = 0; t < 4; ++t) ss += vv[t][r] * vv[t][r];
      #pragma unroll
      for (int off = 1; off < 16; off <<= 1) ss += __shfl_xor(ss, off, 64);
      if (l15 == 0) cmb[wc][lr0 + r][0] = ss;
    }
    __syncthreads();
    #pragma unroll
    for (int r = 0; r < 4; ++r){
      float tot = cmb[0][lr0 + r][0] + cmb[1][lr0 + r][0];
      float sc = 1.f / fmaxf(sqrtf(tot), 1e-12f);
      #pragma unroll
      for (int t = 0; t < 4; ++t) vv[t][r] *= sc;
    }
  }
  #pragma unroll
  for (int t = 0; t < 4; t += 2){
    #pragma unroll
    for (int r = 0; r < 4; ++r){
      int row = lr0 + r;
      int c0 = wc * 64 + t * 16 + l15, c1 = c0 + 16;
      uint_t pr = cvtpk(vv[t][r], vv[t + 1][r]);
      Cs[row * CP + c0] = (ushort_t)pr;
      Cs[row * CP + c1] = (ushort_t)(pr >> 16);
      if (STORE1){
        int g = row0 + row;
        if (g < M){
          out1[(size_t)g * 128 + c0] = (ushort_t)pr;
          out1[(size_t)g * 128 + c1] = (ushort_t)(pr >> 16);
        }
      }
    }
  }
  __syncthreads();

  // ============ GEMM 2: Cs[32 x 128] @ W2^T, B direct from global (L2-hot) ============
  #pragma unroll
  for (int t = 0; t < 4; ++t) acc[t] = (f32x4){0.f, 0.f, 0.f, 0.f};
  {
    const int rr = wr * 16 + l15;
    const ushort_t* w2 = Wb2 + (size_t)(wc * 64 + l15) * 128 + quad * 8;
    #pragma unroll
    for (int kk = 0; kk < 4; ++kk){
      bf16x8 af2 = *reinterpret_cast<const bf16x8*>(&Cs[rr * CP + kk * 32 + quad * 8]);
      #pragma unroll
      for (int t = 0; t < 4; ++t){
        bf16x8 bfr = *reinterpret_cast<const bf16x8*>(w2 + (size_t)t * 16 * 128 + kk * 32);
        acc[t] = __builtin_amdgcn_mfma_f32_16x16x32_bf16(af2, bfr, acc[t], 0, 0, 0);
      }
    }
  }

  // ---- epilogue 2 ----
  if (M2 == 1){
    #pragma unroll
    for (int t = 0; t < 4; ++t){
      #pragma unroll
      for (int r = 0; r < 4; ++r){
        int grow = row0 + lr0 + r;
        if (grow >= M) continue;
        int col = wc * 64 + t * 16 + l15;
        float v = acc[t][r] + vec2[col];
        v = v > 0.f ? v : 0.01f * v;
        ((float*)out2)[(size_t)grow * 128 + col] = v;
      }
    }
  } else { // M2 == 3: bf16 out + per-row sA/sB (cross-wave combine via LDS)
    #pragma unroll
    for (int t = 0; t < 4; t += 2){
      #pragma unroll
      for (int r = 0; r < 4; ++r){
        int grow = row0 + lr0 + r;
        if (grow >= M) continue;
        int c0 = wc * 64 + t * 16 + l15;
        uint_t pr = cvtpk(acc[t][r], acc[t + 1][r]);
        ((ushort_t*)out2)[(size_t)grow * 128 + c0]      = (ushort_t)pr;
        ((ushort_t*)out2)[(size_t)grow * 128 + c0 + 16] = (ushort_t)(pr >> 16);
      }
    }
    #pragma unroll
    for (int r = 0; r < 4; ++r){
      float pa = 0.f, pb = 0.f;
      #pragma unroll
      for (int t = 0; t < 4; ++t){
        int col = wc * 64 + t * 16 + l15;
        pa += acc[t][r] * vec2[col];
        pb += acc[t][r] * vec2[128 + col];
      }
      #pragma unroll
      for (int off = 1; off < 16; off <<= 1){
        pa += __shfl_xor(pa, off, 64);
        pb += __shfl_xor(pb, off, 64);
      }
      if (l15 == 0){ cmb[wc][lr0 + r][0] = pa; cmb[wc][lr0 + r][1] = pb; }
    }
    __syncthreads();
    if (tid < 64){
      int row = tid >> 1, ab = tid & 1;
      float v = cmb[0][row][ab] + cmb[1][row][ab];
      int g = row0 + row;
      if (g < M){ if (ab) sB[g] = v; else sA[g] = v; }
    }
  }
}

// ------- per-node softmax + aggregate: 16-lane group per node (4 nodes/wave) -------
__global__ __launch_bounds__(256) void agg_k(
    const ushort_t* __restrict__ Wx, const float* __restrict__ sA,
    const float* __restrict__ sB, const float* __restrict__ sC,
    const int* __restrict__ rowptr, const int* __restrict__ cpk,
    uint_t* __restrict__ aggU, int n)
{
  const int node  = blockIdx.x * 16 + (threadIdx.x >> 4);
  const int l     = threadIdx.x & 15;    // lane in group
  const int gbase = threadIdx.x & 48;    // group base lane within wave
  if (node >= n) return;
  int p0 = rowptr[node], p1 = rowptr[node + 1];
  int deg = p1 - p0;
  float sa = sA[node];
  float m = -1e30f, ssum = 0.f;
  float a[8];
  #pragma unroll
  for (int j = 0; j < 8; ++j) a[j] = 0.f;

  for (int c0 = 0; c0 < deg; c0 += 16){
    int cnt = deg - c0; if (cnt > 16) cnt = 16;
    bool ok = l < cnt;
    int pk = cpk[p0 + c0 + (ok ? l : 0)];
    float s = sa + sB[pk & 0xFFFF] + sC[pk >> 16];
    s = s > 0.f ? s : 0.2f * s;                    // leaky_relu(., 0.2)
    float sv = ok ? s : -1e30f;
    #pragma unroll
    for (int off = 8; off > 0; off >>= 1) sv = fmaxf(sv, __shfl_xor(sv, off, 16));
    float mn = fmaxf(m, sv);
    float corr = __expf(m - mn);
    ssum *= corr;
    #pragma unroll
    for (int j = 0; j < 8; ++j) a[j] *= corr;
    float ev = ok ? __expf(s - mn) : 0.f;          // ev == 0 on masked lanes
    float es = ev;
    #pragma unroll
    for (int off = 8; off > 0; off >>= 1) es += __shfl_xor(es, off, 16);
    ssum += es;
    m = mn;
    int png = ok ? pk : 0;

    for (int e = 0; e < cnt; e += 4){              // tail edges neutralized by ev=0
      int b0l = gbase + e;
      int pe0 = __shfl(png, b0l,     64), pe1 = __shfl(png, b0l + 1, 64);
      int pe2 = __shfl(png, b0l + 2, 64), pe3 = __shfl(png, b0l + 3, 64);
      float e0 = __shfl(ev, b0l,     64), e1 = __shfl(ev, b0l + 1, 64);
      float e2 = __shfl(ev, b0l + 2, 64), e3 = __shfl(ev, b0l + 3, 64);
      uint4 u0 = *reinterpret_cast<const uint4*>(Wx + (size_t)(pe0 & 0xFFFF) * 128 + l * 8);
      uint4 u1 = *reinterpret_cast<const uint4*>(Wx + (size_t)(pe1 & 0xFFFF) * 128 + l * 8);
      uint4 u2 = *reinterpret_cast<const uint4*>(Wx + (size_t)(pe2 & 0xFFFF) * 128 + l * 8);
      uint4 u3 = *reinterpret_cast<const uint4*>(Wx + (size_t)(pe3 & 0xFFFF) * 128 + l * 8);
      a[0] += e0 * b2f_lo(u0.x); a[1] += e0 * b2f_hi(u0.x);
      a[2] += e0 * b2f_lo(u0.y); a[3] += e0 * b2f_hi(u0.y);
      a[4] += e0 * b2f_lo(u0.z); a[5] += e0 * b2f_hi(u0.z);
      a[6] += e0 * b2f_lo(u0.w); a[7] += e0 * b2f_hi(u0.w);
      a[0] += e1 * b2f_lo(u1.x); a[1] += e1 * b2f_hi(u1.x);
      a[2] += e1 * b2f_lo(u1.y); a[3] += e1 * b2f_hi(u1.y);
      a[4] += e1 * b2f_lo(u1.z); a[5] += e1 * b2f_hi(u1.z);
      a[6] += e1 * b2f_lo(u1.w); a[7] += e1 * b2f_hi(u1.w);
      a[0] += e2 * b2f_lo(u2.x); a[1] += e2 * b2f_hi(u2.x);
      a[2] += e2 * b2f_lo(u2.y); a[3] += e2 * b2f_hi(u2.y);
      a[4] += e2 * b2f_lo(u2.z); a[5] += e2 * b2f_hi(u2.z);
      a[6] += e2 * b2f_lo(u2.w); a[7] += e2 * b2f_hi(u2.w);
      a[0] += e3 * b2f_lo(u3.x); a[1] += e3 * b2f_hi(u3.x);
      a[2] += e3 * b2f_lo(u3.y); a[3] += e3 * b2f_hi(u3.y);
      a[4] += e3 * b2f_lo(u3.z); a[5] += e3 * b2f_hi(u3.z);
      a[6] += e3 * b2f_lo(u3.w); a[7] += e3 * b2f_hi(u3.w);
    }
  }
  float inv = (deg > 0) ? 1.f / ssum : 0.f;        // degree-0 -> zero row
  uint4 o;
  o.x = cvtpk(a[0] * inv, a[1] * inv);
  o.y = cvtpk(a[2] * inv, a[3] * inv);
  o.z = cvtpk(a[4] * inv, a[5] * inv);
  o.w = cvtpk(a[6] * inv, a[7] * inv);
  *reinterpret_cast<uint4*>(aggU + (size_t)node * 64 + l * 4) = o;   // cols l*8..l*8+7
}

} // namespace

extern "C" void kernel_launch(void* const* d_in, const int* in_sizes, int n_in,
                              void* d_out, int out_size, void* d_ws, size_t ws_size,
                              hipStream_t stream)
{
  const float* x     = (const float*)d_in[0];
  const int*   eidx  = (const int*)d_in[1];
  const int*   et    = (const int*)d_in[2];
  const float* l1W   = (const float*)d_in[3];
  const float* l1b   = (const float*)d_in[4];
  const float* l2W   = (const float*)d_in[5];
  const float* l2b   = (const float*)d_in[6];
  const float* W1    = (const float*)d_in[7];
  const float* Wr1   = (const float*)d_in[8];
  const float* a1    = (const float*)d_in[9];
  const float* Wres1 = (const float*)d_in[10];
  const float* rel1  = (const float*)d_in[11];
  const float* W2    = (const float*)d_in[12];
  const float* Wr2   = (const float*)d_in[13];
  const float* a2    = (const float*)d_in[14];
  const float* Wres2 = (const float*)d_in[15];
  const float* rel2  = (const float*)d_in[16];
  float* outp = (float*)d_out;

  const int* esrc = eidx;        // edge_index[0]
  const int* edst = eidx + E;    // edge_index[1]

  // -------- workspace layout --------
  float* f = (float*)d_ws;
  size_t o = 0;
  float* sA   = f + o; o += N;
  float* sB   = f + o; o += N;
  float* sC1  = f + o; o += 8;
  float* sC2  = f + o; o += 8;
  ushort_t* us = (ushort_t*)(f + o);
  size_t ou = 0;
  ushort_t* b0   = us + ou; ou += (size_t)N * H;    // h0 bf16
  ushort_t* b1   = us + ou; ou += (size_t)N * H;    // h1 bf16
  ushort_t* Wxb  = us + ou; ou += (size_t)N * H;    // Wx bf16
  ushort_t* aggB = us + ou; ou += (size_t)N * H;    // agg bf16
  ushort_t* wtsb = us + ou; ou += (size_t)H * KIN + 5 * H * H;
  ushort_t* l1Wb = wtsb;
  ushort_t* W1b  = wtsb + H * KIN;
  ushort_t* R1b  = W1b + H * H;
  ushort_t* W2b  = R1b + H * H;
  ushort_t* R2b  = W2b + H * H;
  ushort_t* l2Wb = R2b + H * H;
  if (ou & 1) ou += 1;
  int* wi = (int*)(us + ou);
  size_t oi = 0;
  int* deg    = wi + oi; oi += N;
  int* rowptr = wi + oi; oi += N + 1;
  int* cursor = wi + oi; oi += N;
  int* bsums  = wi + oi; oi += 256;
  int* boffs  = wi + oi; oi += 256;
  int* cpk    = wi + oi; oi += E;

  const int EB    = (E + 255) / 256;
  const int NB256 = (N + 255) / 256;
  const int GB    = (N + 31) / 32;
  const int NB16  = (N + 15) / 16;

  // -------- prep (weight cvt + deg zero + relsc) & CSR build --------
  prep_k<<<902, 256, 0, stream>>>(l1W, W1, Wres1, W2, Wres2, l2W, wtsb, deg,
                                  rel1, Wr1, a1, sC1, rel2, Wr2, a2, sC2);
  degcount_k<<<EB, 256, 0, stream>>>(edst, deg);
  scan1_k<<<NB256, 256, 0, stream>>>(deg, rowptr, bsums, N);
  scan2_k<<<1, 256, 0, stream>>>(bsums, boffs, NB256);
  scan3_k<<<NB256, 256, 0, stream>>>(rowptr, boffs, cursor, N, E);
  fill_k<<<EB, 256, 0, stream>>>(esrc, edst, et, cursor, cpk);

  // -------- G1: h0 = leaky(x@l1W^T+b) -> b0;  Wx1 = h0@W1^T -> Wxb (+sA/sB) --------
  gfused_k<KIN, 1, true, false, true, 3><<<GB, 256, 0, stream>>>(
      x, l1Wb, l1b, nullptr, b0, W1b, a1, Wxb, sA, sB, N);
  agg_k<<<NB16, 256, 0, stream>>>(Wxb, sA, sB, sC1, rowptr, cpk, (uint_t*)aggB, N);

  // -------- G2: h1 = elu(agg1 + b0@R1^T) -> b1;  Wx2 = h1@W2^T -> Wxb (+sA/sB) --------
  gfused_k<H, 2, false, false, true, 3><<<GB, 256, 0, stream>>>(
      b0, R1b, nullptr, aggB, b1, W2b, a2, Wxb, sA, sB, N);
  agg_k<<<NB16, 256, 0, stream>>>(Wxb, sA, sB, sC2, rowptr, cpk, (uint_t*)aggB, N);

  // -------- G3: h2 = normalize(elu(agg2 + b1@R2^T));  out = leaky(h2@l2W^T+b) --------
  gfused_k<H, 2, false, true, false, 1><<<GB, 256, 0, stream>>>(
      b1, R2b, nullptr, aggB, nullptr, l2Wb, l2b, outp, nullptr, nullptr, N);
}

// Round 5
// 501.519 us; speedup vs baseline: 1.1470x; 1.0290x over previous
//
#include <hip/hip_runtime.h>

namespace {

typedef unsigned short ushort_t;
typedef unsigned int uint_t;
typedef __attribute__((ext_vector_type(8))) short bf16x8;
typedef __attribute__((ext_vector_type(4))) float f32x4;

constexpr int N   = 50000;
constexpr int E   = 600000;
constexpr int NR  = 5;
constexpr int KIN = 768;
constexpr int H   = 128;
constexpr int RD  = 200;

__device__ inline ushort_t f2b(float f){           // fp32 -> bf16 bits, RNE
  uint_t u = __builtin_bit_cast(uint_t, f);
  uint_t r = (u + 0x7FFFu + ((u >> 16) & 1u)) >> 16;
  return (ushort_t)r;
}
__device__ inline float b2f_lo(uint_t u){ return __builtin_bit_cast(float, u << 16); }
__device__ inline float b2f_hi(uint_t u){ return __builtin_bit_cast(float, u & 0xFFFF0000u); }
__device__ inline float b2f_us(ushort_t h){ return __builtin_bit_cast(float, ((uint_t)h) << 16); }
__device__ inline uint_t cvtpk(float lo, float hi){ // 2x fp32 -> packed bf16 (RNE), 1 instr
  uint_t r;
  asm("v_cvt_pk_bf16_f32 %0, %1, %2" : "=v"(r) : "v"(lo), "v"(hi));
  return r;
}

// ---- prep: weight cvt (blocks 0..703) + relsc (704..705) + degcount (706..) ----
// deg[] is zeroed by hipMemsetAsync before this launch, so degcount can run
// concurrently with the weight conversion (independent blocks, one dispatch).
__global__ void prep_k(const float* __restrict__ l1W, const float* __restrict__ W1,
                       const float* __restrict__ R1, const float* __restrict__ W2,
                       const float* __restrict__ R2, const float* __restrict__ l2W,
                       ushort_t* __restrict__ wts, int* __restrict__ deg,
                       const int* __restrict__ edst,
                       const float* __restrict__ rel1, const float* __restrict__ Wr1,
                       const float* __restrict__ a1, float* __restrict__ sC1,
                       const float* __restrict__ rel2, const float* __restrict__ Wr2,
                       const float* __restrict__ a2, float* __restrict__ sC2){
  constexpr int S0 = H * KIN;        // 98304
  constexpr int S1 = H * H;          // 16384
  int b = blockIdx.x, tid = threadIdx.x;
  if (b < 704){                      // weight convert: 704*256 == S0 + 5*S1 exactly
    int i = b * 256 + tid;
    float v;
    if (i < S0) v = l1W[i];
    else {
      int j = i - S0, seg = j >> 14, off = j & (S1 - 1);
      const float* srcs[5] = {W1, R1, W2, R2, l2W};
      v = srcs[seg][off];
    }
    wts[i] = f2b(v);
  } else if (b < 706){               // relation scalars, one block per layer
    int L = b - 704;
    const float* rel = L ? rel2 : rel1;
    const float* Wr  = L ? Wr2  : Wr1;
    const float* a   = L ? a2   : a1;
    float*       sC  = L ? sC2  : sC1;
    __shared__ float red[256];
    int n = tid >> 1, half = tid & 1;
    float aC = a[256 + n];
    for (int r = 0; r < NR; ++r){
      float p = 0.f;
      for (int k = half * 100; k < half * 100 + 100; ++k)
        p += rel[r * RD + k] * Wr[n * RD + k];
      red[tid] = p * aC;
      __syncthreads();
      for (int s = 128; s > 0; s >>= 1){
        if (tid < s) red[tid] += red[tid + s];
        __syncthreads();
      }
      if (tid == 0) sC[r] = red[0];
      __syncthreads();
    }
  } else {                           // degree count
    int e = (b - 706) * 256 + tid;
    if (e < E) atomicAdd(&deg[edst[e]], 1);
  }
}

// ---------------- CSR build ----------------
__global__ void scan1_k(const int* __restrict__ deg, int* __restrict__ chunk,
                        int* __restrict__ bsums, int n){
  __shared__ int s[256];
  int tid = threadIdx.x, i = blockIdx.x * 256 + tid;
  int v = (i < n) ? deg[i] : 0;
  s[tid] = v; __syncthreads();
  for (int off = 1; off < 256; off <<= 1){
    int t = (tid >= off) ? s[tid - off] : 0;
    __syncthreads();
    s[tid] += t;
    __syncthreads();
  }
  if (i < n) chunk[i] = s[tid] - v;
  if (tid == 255) bsums[blockIdx.x] = s[255];
}

__global__ void scan2_k(const int* __restrict__ bsums, int* __restrict__ boffs, int nb){
  __shared__ int s[256];
  int tid = threadIdx.x;
  int v = (tid < nb) ? bsums[tid] : 0;
  s[tid] = v; __syncthreads();
  for (int off = 1; off < 256; off <<= 1){
    int t = (tid >= off) ? s[tid - off] : 0;
    __syncthreads();
    s[tid] += t;
    __syncthreads();
  }
  if (tid < nb) boffs[tid] = s[tid] - v;
}

__global__ void scan3_k(int* __restrict__ rowptr, const int* __restrict__ boffs,
                        int* __restrict__ cursor, int n, int total){
  int i = blockIdx.x * 256 + threadIdx.x;
  if (i < n){
    int v = rowptr[i] + boffs[blockIdx.x];
    rowptr[i] = v; cursor[i] = v;
  }
  if (i == 0) rowptr[n] = total;
}

// fill CSR adjacency with (type<<16)|src packed (src < 65536, type < 8)
__global__ void fill_k(const int* __restrict__ src, const int* __restrict__ dst,
                       const int* __restrict__ et, int* __restrict__ cursor,
                       int* __restrict__ cpk){
  int e = blockIdx.x * 256 + threadIdx.x;
  if (e < E){
    int d = dst[e];
    int p = atomicAdd(&cursor[d], 1);
    cpk[p] = src[e] | (et[e] << 16);
  }
}

// --------- fused [agg +] double-GEMM: out1 = f1(A @ W1^T [+agg]), out2 = f2(out1 @ W2^T) ---------
// W matrices bf16 in original [out][in] layout == MFMA B-operand [n][k] layout.
// 256 thr / 4 waves; tile 64 rows x 128 cols; wave w owns rows w*16..+15.
// M1 == 2: block FIRST computes the softmax-aggregation for its own 64 rows
// (16-lane group per node, gathering Wx rows from global) straight into the Cs
// LDS tile -- no agg kernel, no global agg round-trip; the gather latency of
// one block overlaps the GEMM phases of other resident blocks.
// GEMM1: 2-phase reg-staged prefetch (next k-tile loads issued between barriers).
// GEMM2: whole 128x128 B staged once in LDS overlaid on the dead As/Bs region.
// M1: 1 = +bias1, leaky(0.01)    2 = elu(acc + agg)
// NORM: fused row L2-normalize after f1;  STORE1: write stage-1 bf16 to out1
// M2: 1 = +vec2 bias, leaky(0.01), fp32 out2    3 = bf16 out2 + sA/sB (vec2 = a)
template<int K1, int M1, bool AFP32, bool NORM, bool STORE1, int M2>
__global__ __launch_bounds__(256) void gfused_k(
    const void* __restrict__ Ap, const ushort_t* __restrict__ Wb1,
    const float* __restrict__ bias1,
    const ushort_t* __restrict__ WxG, const int* __restrict__ rowptr,
    const int* __restrict__ cpk, const float* __restrict__ sAi,
    const float* __restrict__ sBi, const float* __restrict__ sCi,
    ushort_t* __restrict__ out1,
    const ushort_t* __restrict__ Wb2, const float* __restrict__ vec2,
    void* __restrict__ out2, float* __restrict__ sAo, float* __restrict__ sBo, int M)
{
  constexpr int AP = 40;   // k-tile staging strides (bf16 elems); 80B rows, 16B aligned
  constexpr int BP = 40;
  constexpr int CP = 136;  // stage-1 result / B2 tile stride; 272B rows, 16B aligned
  __shared__ __align__(16) ushort_t U[128 * CP];   // 34816 B: As+Bs (GEMM1) | B2s (GEMM2)
  __shared__ __align__(16) ushort_t Cs[64 * CP];   // 17408 B
  ushort_t* const As  = U;              // 64 x AP
  ushort_t* const Bs  = U + 64 * AP;    // 128 x BP (ends at 15360 B < 34816)
  ushort_t* const B2s = U;              // 128 x CP, valid after GEMM1 completes
  const int tid  = threadIdx.x;
  const int wave = tid >> 6, lane = tid & 63;
  const int l15  = lane & 15, quad = lane >> 4;
  const int row0 = blockIdx.x * 64;

  // ---- M1==2: in-block aggregation for this block's 64 nodes -> Cs ----
  if (M1 == 2){
    const int grp = tid >> 4;       // 16 groups of 16 lanes
    const int l   = tid & 15;
    const int gb  = tid & 48;       // group base lane within wave
    #pragma unroll 1
    for (int nb = 0; nb < 4; ++nb){
      int lrow = nb * 16 + grp;
      int node = row0 + lrow;
      uint4 o = make_uint4(0, 0, 0, 0);
      if (node < M){
        int p0 = rowptr[node], p1 = rowptr[node + 1];
        int dg = p1 - p0;
        float sa = sAi[node];
        float m = -1e30f, ssum = 0.f;
        float a[8];
        #pragma unroll
        for (int j = 0; j < 8; ++j) a[j] = 0.f;
        for (int c0 = 0; c0 < dg; c0 += 16){
          int cnt = dg - c0; if (cnt > 16) cnt = 16;
          bool ok = l < cnt;
          int pk = cpk[p0 + c0 + (ok ? l : 0)];
          float s = sa + sBi[pk & 0xFFFF] + sCi[pk >> 16];
          s = s > 0.f ? s : 0.2f * s;                    // leaky_relu(., 0.2)
          float sv = ok ? s : -1e30f;
          #pragma unroll
          for (int off = 8; off > 0; off >>= 1) sv = fmaxf(sv, __shfl_xor(sv, off, 16));
          float mn = fmaxf(m, sv);
          float corr = __expf(m - mn);
          ssum *= corr;
          #pragma unroll
          for (int j = 0; j < 8; ++j) a[j] *= corr;
          float ev = ok ? __expf(s - mn) : 0.f;          // ev == 0 on masked lanes
          float es = ev;
          #pragma unroll
          for (int off = 8; off > 0; off >>= 1) es += __shfl_xor(es, off, 16);
          ssum += es;
          m = mn;
          int png = ok ? pk : 0;
          for (int e = 0; e < cnt; e += 4){              // tails neutralized by ev=0
            int b0l = gb + e;
            int pe0 = __shfl(png, b0l,     64), pe1 = __shfl(png, b0l + 1, 64);
            int pe2 = __shfl(png, b0l + 2, 64), pe3 = __shfl(png, b0l + 3, 64);
            float e0 = __shfl(ev, b0l,     64), e1 = __shfl(ev, b0l + 1, 64);
            float e2 = __shfl(ev, b0l + 2, 64), e3 = __shfl(ev, b0l + 3, 64);
            uint4 u0 = *reinterpret_cast<const uint4*>(WxG + (size_t)(pe0 & 0xFFFF) * 128 + l * 8);
            uint4 u1 = *reinterpret_cast<const uint4*>(WxG + (size_t)(pe1 & 0xFFFF) * 128 + l * 8);
            uint4 u2 = *reinterpret_cast<const uint4*>(WxG + (size_t)(pe2 & 0xFFFF) * 128 + l * 8);
            uint4 u3 = *reinterpret_cast<const uint4*>(WxG + (size_t)(pe3 & 0xFFFF) * 128 + l * 8);
            a[0] += e0 * b2f_lo(u0.x); a[1] += e0 * b2f_hi(u0.x);
            a[2] += e0 * b2f_lo(u0.y); a[3] += e0 * b2f_hi(u0.y);
            a[4] += e0 * b2f_lo(u0.z); a[5] += e0 * b2f_hi(u0.z);
            a[6] += e0 * b2f_lo(u0.w); a[7] += e0 * b2f_hi(u0.w);
            a[0] += e1 * b2f_lo(u1.x); a[1] += e1 * b2f_hi(u1.x);
            a[2] += e1 * b2f_lo(u1.y); a[3] += e1 * b2f_hi(u1.y);
            a[4] += e1 * b2f_lo(u1.z); a[5] += e1 * b2f_hi(u1.z);
            a[6] += e1 * b2f_lo(u1.w); a[7] += e1 * b2f_hi(u1.w);
            a[0] += e2 * b2f_lo(u2.x); a[1] += e2 * b2f_hi(u2.x);
            a[2] += e2 * b2f_lo(u2.y); a[3] += e2 * b2f_hi(u2.y);
            a[4] += e2 * b2f_lo(u2.z); a[5] += e2 * b2f_hi(u2.z);
            a[6] += e2 * b2f_lo(u2.w); a[7] += e2 * b2f_hi(u2.w);
            a[0] += e3 * b2f_lo(u3.x); a[1] += e3 * b2f_hi(u3.x);
            a[2] += e3 * b2f_lo(u3.y); a[3] += e3 * b2f_hi(u3.y);
            a[4] += e3 * b2f_lo(u3.z); a[5] += e3 * b2f_hi(u3.z);
            a[6] += e3 * b2f_lo(u3.w); a[7] += e3 * b2f_hi(u3.w);
          }
        }
        float inv = (dg > 0) ? 1.f / ssum : 0.f;        // degree-0 -> zero row
        o.x = cvtpk(a[0] * inv, a[1] * inv);
        o.y = cvtpk(a[2] * inv, a[3] * inv);
        o.z = cvtpk(a[4] * inv, a[5] * inv);
        o.w = cvtpk(a[6] * inv, a[7] * inv);
      }
      *reinterpret_cast<uint4*>(&Cs[lrow * CP + l * 8]) = o;   // cols l*8..l*8+7
    }
  }

  f32x4 acc[8];
  #pragma unroll
  for (int t = 0; t < 8; ++t) acc[t] = (f32x4){0.f, 0.f, 0.f, 0.f};

  // ================= GEMM 1: A[M x K1] @ W1^T, prefetched =================
  const int ar = tid >> 2, aq = tid & 3;     // A stage: row 0..63, k-quarter
  const int agrow = row0 + ar;
  const bool aok = agrow < M;
  const int bn = tid >> 1, bs16 = (tid & 1) * 16;  // B stage: n-row, k-half

  float4 pf0 = make_float4(0.f, 0.f, 0.f, 0.f), pf1 = pf0;
  uint4  pu  = make_uint4(0, 0, 0, 0);
  uint4  pb0, pb1;

  if (AFP32){
    if (aok){
      const float* ap = (const float*)Ap + (size_t)agrow * K1 + aq * 8;
      pf0 = *reinterpret_cast<const float4*>(ap);
      pf1 = *reinterpret_cast<const float4*>(ap + 4);
    }
  } else if (aok){
    pu = *reinterpret_cast<const uint4*>((const ushort_t*)Ap + (size_t)agrow * K1 + aq * 8);
  }
  {
    const ushort_t* wp = Wb1 + (size_t)bn * K1 + bs16;
    pb0 = *reinterpret_cast<const uint4*>(wp);
    pb1 = *reinterpret_cast<const uint4*>(wp + 8);
  }

  for (int k0 = 0; k0 < K1; k0 += 32){
    uint4 av;
    if (AFP32){
      av.x = cvtpk(pf0.x, pf0.y); av.y = cvtpk(pf0.z, pf0.w);
      av.z = cvtpk(pf1.x, pf1.y); av.w = cvtpk(pf1.z, pf1.w);
    } else av = pu;
    *reinterpret_cast<uint4*>(&As[ar * AP + aq * 8]) = av;
    *reinterpret_cast<uint4*>(&Bs[bn * BP + bs16])     = pb0;
    *reinterpret_cast<uint4*>(&Bs[bn * BP + bs16 + 8]) = pb1;
    __syncthreads();
    if (k0 + 32 < K1){               // issue next-tile loads; overlap with MFMAs below
      const int k1 = k0 + 32;
      if (AFP32){
        if (aok){
          const float* ap = (const float*)Ap + (size_t)agrow * K1 + k1 + aq * 8;
          pf0 = *reinterpret_cast<const float4*>(ap);
          pf1 = *reinterpret_cast<const float4*>(ap + 4);
        }
      } else if (aok){
        pu = *reinterpret_cast<const uint4*>((const ushort_t*)Ap + (size_t)agrow * K1 + k1 + aq * 8);
      }
      const ushort_t* wp = Wb1 + (size_t)bn * K1 + k1 + bs16;
      pb0 = *reinterpret_cast<const uint4*>(wp);
      pb1 = *reinterpret_cast<const uint4*>(wp + 8);
    }
    bf16x8 af = *reinterpret_cast<const bf16x8*>(&As[(wave * 16 + l15) * AP + quad * 8]);
    #pragma unroll
    for (int t = 0; t < 8; ++t){
      bf16x8 bfr = *reinterpret_cast<const bf16x8*>(&Bs[(t * 16 + l15) * BP + quad * 8]);
      acc[t] = __builtin_amdgcn_mfma_f32_16x16x32_bf16(af, bfr, acc[t], 0, 0, 0);
    }
    __syncthreads();
  }

  // ---- issue GEMM2 B loads first (latency hides under epilogue-1 VALU) ----
  uint4 wreg[8];
  #pragma unroll
  for (int i = 0; i < 8; ++i){
    int idx = tid + 256 * i;                 // 2048 chunks of 8 bf16
    int rr = idx >> 4, c8 = idx & 15;
    wreg[i] = *reinterpret_cast<const uint4*>(Wb2 + (size_t)rr * 128 + c8 * 8);
  }

  // ---- epilogue 1: C/D map col=t*16+l15, local row lr=wave*16+quad*4+r ----
  float vv[8][4];
  #pragma unroll
  for (int t = 0; t < 8; ++t){
    #pragma unroll
    for (int r = 0; r < 4; ++r){
      int lr  = wave * 16 + quad * 4 + r;
      int col = t * 16 + l15;
      float v = acc[t][r];
      if (M1 == 1){
        v += bias1[col];
        v = v > 0.f ? v : 0.01f * v;
      } else { // M1 == 2
        v += b2f_us(Cs[lr * CP + col]);      // same cell this thread rewrites below
        v = v > 0.f ? v : __expf(v) - 1.f;
      }
      vv[t][r] = v;
    }
  }
  // write staged B2 (As/Bs region dead after last k-loop barrier)
  #pragma unroll
  for (int i = 0; i < 8; ++i){
    int idx = tid + 256 * i;
    int rr = idx >> 4, c8 = idx & 15;
    *reinterpret_cast<uint4*>(&B2s[rr * CP + c8 * 8]) = wreg[i];
  }
  if (NORM){
    #pragma unroll
    for (int r = 0; r < 4; ++r){
      float ss = 0.f;
      #pragma unroll
      for (int t = 0; t < 8; ++t) ss += vv[t][r] * vv[t][r];
      #pragma unroll
      for (int off = 1; off < 16; off <<= 1) ss += __shfl_xor(ss, off, 64);
      float sc = 1.f / fmaxf(sqrtf(ss), 1e-12f);
      #pragma unroll
      for (int t = 0; t < 8; ++t) vv[t][r] *= sc;
    }
  }
  #pragma unroll
  for (int t = 0; t < 8; t += 2){
    #pragma unroll
    for (int r = 0; r < 4; ++r){
      int lr  = wave * 16 + quad * 4 + r;
      int c0  = t * 16 + l15, c1 = c0 + 16;
      uint_t pr = cvtpk(vv[t][r], vv[t + 1][r]);
      Cs[lr * CP + c0] = (ushort_t)pr;
      Cs[lr * CP + c1] = (ushort_t)(pr >> 16);
      if (STORE1){
        int grow = row0 + lr;
        if (grow < M){
          out1[(size_t)grow * 128 + c0] = (ushort_t)pr;
          out1[(size_t)grow * 128 + c1] = (ushort_t)(pr >> 16);
        }
      }
    }
  }
  __syncthreads();

  // ================= GEMM 2: Cs[64 x 128] @ W2^T, fully staged, no barriers =================
  #pragma unroll
  for (int t = 0; t < 8; ++t) acc[t] = (f32x4){0.f, 0.f, 0.f, 0.f};
  #pragma unroll
  for (int kk = 0; kk < 4; ++kk){
    bf16x8 af2 = *reinterpret_cast<const bf16x8*>(&Cs[(wave * 16 + l15) * CP + kk * 32 + quad * 8]);
    #pragma unroll
    for (int t = 0; t < 8; ++t){
      bf16x8 bfr = *reinterpret_cast<const bf16x8*>(&B2s[(t * 16 + l15) * CP + kk * 32 + quad * 8]);
      acc[t] = __builtin_amdgcn_mfma_f32_16x16x32_bf16(af2, bfr, acc[t], 0, 0, 0);
    }
  }

  // ---- epilogue 2 ----
  if (M2 == 1){
    #pragma unroll
    for (int t = 0; t < 8; ++t){
      #pragma unroll
      for (int r = 0; r < 4; ++r){
        int grow = row0 + wave * 16 + quad * 4 + r;
        if (grow >= M) continue;
        int col = t * 16 + l15;
        float v = acc[t][r] + vec2[col];
        v = v > 0.f ? v : 0.01f * v;
        ((float*)out2)[(size_t)grow * 128 + col] = v;
      }
    }
  } else { // M2 == 3: bf16 out + per-row sA/sB
    #pragma unroll
    for (int t = 0; t < 8; t += 2){
      #pragma unroll
      for (int r = 0; r < 4; ++r){
        int grow = row0 + wave * 16 + quad * 4 + r;
        if (grow >= M) continue;
        int c0 = t * 16 + l15;
        uint_t pr = cvtpk(acc[t][r], acc[t + 1][r]);
        ((ushort_t*)out2)[(size_t)grow * 128 + c0]      = (ushort_t)pr;
        ((ushort_t*)out2)[(size_t)grow * 128 + c0 + 16] = (ushort_t)(pr >> 16);
      }
    }
    #pragma unroll
    for (int r = 0; r < 4; ++r){
      float pa = 0.f, pb = 0.f;
      #pragma unroll
      for (int t = 0; t < 8; ++t){
        int col = t * 16 + l15;
        pa += acc[t][r] * vec2[col];
        pb += acc[t][r] * vec2[128 + col];
      }
      #pragma unroll
      for (int off = 1; off < 16; off <<= 1){
        pa += __shfl_xor(pa, off, 64);
        pb += __shfl_xor(pb, off, 64);
      }
      int grow = row0 + wave * 16 + quad * 4 + r;
      if (l15 == r && grow < M){ sAo[grow] = pa; sBo[grow] = pb; }
    }
  }
}

} // namespace

extern "C" void kernel_launch(void* const* d_in, const int* in_sizes, int n_in,
                              void* d_out, int out_size, void* d_ws, size_t ws_size,
                              hipStream_t stream)
{
  const float* x     = (const float*)d_in[0];
  const int*   eidx  = (const int*)d_in[1];
  const int*   et    = (const int*)d_in[2];
  const float* l1W   = (const float*)d_in[3];
  const float* l1b   = (const float*)d_in[4];
  const float* l2W   = (const float*)d_in[5];
  const float* l2b   = (const float*)d_in[6];
  const float* W1    = (const float*)d_in[7];
  const float* Wr1   = (const float*)d_in[8];
  const float* a1    = (const float*)d_in[9];
  const float* Wres1 = (const float*)d_in[10];
  const float* rel1  = (const float*)d_in[11];
  const float* W2    = (const float*)d_in[12];
  const float* Wr2   = (const float*)d_in[13];
  const float* a2    = (const float*)d_in[14];
  const float* Wres2 = (const float*)d_in[15];
  const float* rel2  = (const float*)d_in[16];
  float* outp = (float*)d_out;

  const int* esrc = eidx;        // edge_index[0]
  const int* edst = eidx + E;    // edge_index[1]

  // -------- workspace layout --------
  float* f = (float*)d_ws;
  size_t o = 0;
  float* sA1  = f + o; o += N;
  float* sB1  = f + o; o += N;
  float* sA2  = f + o; o += N;
  float* sB2  = f + o; o += N;
  float* sC1  = f + o; o += 8;
  float* sC2  = f + o; o += 8;
  ushort_t* us = (ushort_t*)(f + o);
  size_t ou = 0;
  ushort_t* b0   = us + ou; ou += (size_t)N * H;    // h0 bf16
  ushort_t* b1   = us + ou; ou += (size_t)N * H;    // h1 bf16
  ushort_t* WxA  = us + ou; ou += (size_t)N * H;    // Wx layer-1 bf16
  ushort_t* WxB  = us + ou; ou += (size_t)N * H;    // Wx layer-2 bf16
  ushort_t* wtsb = us + ou; ou += (size_t)H * KIN + 5 * H * H;
  ushort_t* l1Wb = wtsb;
  ushort_t* W1b  = wtsb + H * KIN;
  ushort_t* R1b  = W1b + H * H;
  ushort_t* W2b  = R1b + H * H;
  ushort_t* R2b  = W2b + H * H;
  ushort_t* l2Wb = R2b + H * H;
  if (ou & 1) ou += 1;
  int* wi = (int*)(us + ou);
  size_t oi = 0;
  int* deg    = wi + oi; oi += N;
  int* rowptr = wi + oi; oi += N + 1;
  int* cursor = wi + oi; oi += N;
  int* bsums  = wi + oi; oi += 256;
  int* boffs  = wi + oi; oi += 256;
  int* cpk    = wi + oi; oi += E;

  const int EB    = (E + 255) / 256;
  const int NB256 = (N + 255) / 256;
  const int GB    = (N + 63) / 64;

  // -------- prep (deg zero via memset; weight cvt + relsc + degcount fused) --------
  hipMemsetAsync(deg, 0, (size_t)N * sizeof(int), stream);
  prep_k<<<706 + EB, 256, 0, stream>>>(l1W, W1, Wres1, W2, Wres2, l2W, wtsb, deg,
                                       edst, rel1, Wr1, a1, sC1, rel2, Wr2, a2, sC2);
  scan1_k<<<NB256, 256, 0, stream>>>(deg, rowptr, bsums, N);
  scan2_k<<<1, 256, 0, stream>>>(bsums, boffs, NB256);
  scan3_k<<<NB256, 256, 0, stream>>>(rowptr, boffs, cursor, N, E);
  fill_k<<<EB, 256, 0, stream>>>(esrc, edst, et, cursor, cpk);

  // -------- G1: h0 = leaky(x@l1W^T+b) -> b0;  Wx1 = h0@W1^T -> WxA (+sA1/sB1) --------
  gfused_k<KIN, 1, true, false, true, 3><<<GB, 256, 0, stream>>>(
      x, l1Wb, l1b, nullptr, nullptr, nullptr, nullptr, nullptr, nullptr,
      b0, W1b, a1, WxA, sA1, sB1, N);

  // -------- G2': agg1 (in-block) ; h1 = elu(agg1 + b0@R1^T) -> b1; Wx2 -> WxB --------
  gfused_k<H, 2, false, false, true, 3><<<GB, 256, 0, stream>>>(
      b0, R1b, nullptr, WxA, rowptr, cpk, sA1, sB1, sC1,
      b1, W2b, a2, WxB, sA2, sB2, N);

  // -------- G3': agg2 (in-block) ; h2 = normalize(elu(agg2 + b1@R2^T)); out --------
  gfused_k<H, 2, false, true, false, 1><<<GB, 256, 0, stream>>>(
      b1, R2b, nullptr, WxB, rowptr, cpk, sA2, sB2, sC2,
      nullptr, l2Wb, l2b, outp, nullptr, nullptr, N);
}

// Round 6
// 481.726 us; speedup vs baseline: 1.1941x; 1.0411x over previous
//
#include <hip/hip_runtime.h>

namespace {

typedef unsigned short ushort_t;
typedef unsigned int uint_t;
typedef __attribute__((ext_vector_type(8))) short bf16x8;
typedef __attribute__((ext_vector_type(4))) float f32x4;

constexpr int N   = 50000;
constexpr int E   = 600000;
constexpr int NR  = 5;
constexpr int KIN = 768;
constexpr int H   = 128;
constexpr int RD  = 200;

__device__ inline ushort_t f2b(float f){           // fp32 -> bf16 bits, RNE
  uint_t u = __builtin_bit_cast(uint_t, f);
  uint_t r = (u + 0x7FFFu + ((u >> 16) & 1u)) >> 16;
  return (ushort_t)r;
}
__device__ inline float b2f_lo(uint_t u){ return __builtin_bit_cast(float, u << 16); }
__device__ inline float b2f_hi(uint_t u){ return __builtin_bit_cast(float, u & 0xFFFF0000u); }
__device__ inline float b2f_us(ushort_t h){ return __builtin_bit_cast(float, ((uint_t)h) << 16); }
__device__ inline uint_t cvtpk(float lo, float hi){ // 2x fp32 -> packed bf16 (RNE), 1 instr
  uint_t r;
  asm("v_cvt_pk_bf16_f32 %0, %1, %2" : "=v"(r) : "v"(lo), "v"(hi));
  return r;
}

// ---- prep: weight cvt (blocks 0..703) + relsc (704..705) + degcount (706..) ----
__global__ void prep_k(const float* __restrict__ l1W, const float* __restrict__ W1,
                       const float* __restrict__ R1, const float* __restrict__ W2,
                       const float* __restrict__ R2, const float* __restrict__ l2W,
                       ushort_t* __restrict__ wts, int* __restrict__ deg,
                       const int* __restrict__ edst,
                       const float* __restrict__ rel1, const float* __restrict__ Wr1,
                       const float* __restrict__ a1, float* __restrict__ sC1,
                       const float* __restrict__ rel2, const float* __restrict__ Wr2,
                       const float* __restrict__ a2, float* __restrict__ sC2){
  constexpr int S0 = H * KIN;        // 98304
  constexpr int S1 = H * H;          // 16384
  int b = blockIdx.x, tid = threadIdx.x;
  if (b < 704){                      // weight convert: 704*256 == S0 + 5*S1 exactly
    int i = b * 256 + tid;
    float v;
    if (i < S0) v = l1W[i];
    else {
      int j = i - S0, seg = j >> 14, off = j & (S1 - 1);
      const float* srcs[5] = {W1, R1, W2, R2, l2W};
      v = srcs[seg][off];
    }
    wts[i] = f2b(v);
  } else if (b < 706){               // relation scalars, one block per layer
    int L = b - 704;
    const float* rel = L ? rel2 : rel1;
    const float* Wr  = L ? Wr2  : Wr1;
    const float* a   = L ? a2   : a1;
    float*       sC  = L ? sC2  : sC1;
    __shared__ float red[256];
    int n = tid >> 1, half = tid & 1;
    float aC = a[256 + n];
    for (int r = 0; r < NR; ++r){
      float p = 0.f;
      for (int k = half * 100; k < half * 100 + 100; ++k)
        p += rel[r * RD + k] * Wr[n * RD + k];
      red[tid] = p * aC;
      __syncthreads();
      for (int s = 128; s > 0; s >>= 1){
        if (tid < s) red[tid] += red[tid + s];
        __syncthreads();
      }
      if (tid == 0) sC[r] = red[0];
      __syncthreads();
    }
  } else {                           // degree count
    int e = (b - 706) * 256 + tid;
    if (e < E) atomicAdd(&deg[edst[e]], 1);
  }
}

// ---------------- CSR build ----------------
__global__ void scan1_k(const int* __restrict__ deg, int* __restrict__ chunk,
                        int* __restrict__ bsums, int n){
  __shared__ int s[256];
  int tid = threadIdx.x, i = blockIdx.x * 256 + tid;
  int v = (i < n) ? deg[i] : 0;
  s[tid] = v; __syncthreads();
  for (int off = 1; off < 256; off <<= 1){
    int t = (tid >= off) ? s[tid - off] : 0;
    __syncthreads();
    s[tid] += t;
    __syncthreads();
  }
  if (i < n) chunk[i] = s[tid] - v;
  if (tid == 255) bsums[blockIdx.x] = s[255];
}

__global__ void scan2_k(const int* __restrict__ bsums, int* __restrict__ boffs, int nb){
  __shared__ int s[256];
  int tid = threadIdx.x;
  int v = (tid < nb) ? bsums[tid] : 0;
  s[tid] = v; __syncthreads();
  for (int off = 1; off < 256; off <<= 1){
    int t = (tid >= off) ? s[tid - off] : 0;
    __syncthreads();
    s[tid] += t;
    __syncthreads();
  }
  if (tid < nb) boffs[tid] = s[tid] - v;
}

__global__ void scan3_k(int* __restrict__ rowptr, const int* __restrict__ boffs,
                        int* __restrict__ cursor, int n, int total){
  int i = blockIdx.x * 256 + threadIdx.x;
  if (i < n){
    int v = rowptr[i] + boffs[blockIdx.x];
    rowptr[i] = v; cursor[i] = v;
  }
  if (i == 0) rowptr[n] = total;
}

// fill CSR adjacency with (type<<16)|src packed (src < 65536, type < 8)
__global__ void fill_k(const int* __restrict__ src, const int* __restrict__ dst,
                       const int* __restrict__ et, int* __restrict__ cursor,
                       int* __restrict__ cpk){
  int e = blockIdx.x * 256 + threadIdx.x;
  if (e < E){
    int d = dst[e];
    int p = atomicAdd(&cursor[d], 1);
    cpk[p] = src[e] | (et[e] << 16);
  }
}

// --------- fused [agg +] double-GEMM, shared impl; BK=64 k-step ---------
// 64x128 tile, 4 waves, 2-phase reg prefetch; GEMM2 B staged in dead U region.
// M1: 1 = +bias1, leaky(0.01)    2 = in-block agg (16-lane grp/node) + elu(acc+agg)
// NORM: row L2-normalize; STORE1: bf16 stage-1 out; M2: 1 = fp32 out, 3 = bf16 + sA/sB
template<int K1, int M1, bool AFP32, bool NORM, bool STORE1, int M2>
__device__ __forceinline__ void gfused_impl(
    const void* __restrict__ Ap, const ushort_t* __restrict__ Wb1,
    const float* __restrict__ bias1,
    const ushort_t* __restrict__ WxG, const int* __restrict__ rowptr,
    const int* __restrict__ cpk, const float* __restrict__ sAi,
    const float* __restrict__ sBi, const float* __restrict__ sCi,
    ushort_t* __restrict__ out1,
    const ushort_t* __restrict__ Wb2, const float* __restrict__ vec2,
    void* __restrict__ out2, float* __restrict__ sAo, float* __restrict__ sBo, int M)
{
  constexpr int BK = 64;               // k-step
  constexpr int NT = K1 / BK;          // 12 (G1) or 2 (G2/G3)
  constexpr int SP = 72;               // staging row stride (bf16 elems), 144 B
  constexpr int CP = 136;              // Cs/B2s stride; 272 B rows
  __shared__ __align__(16) ushort_t U[128 * CP];   // 34816 B: As+Bs | B2s overlay
  __shared__ __align__(16) ushort_t Cs[64 * CP];   // 17408 B
  ushort_t* const As  = U;                          // 64 x SP   (9216 B)
  ushort_t* const Bs  = U + 64 * SP;                // 128 x SP  (18432 B; tot 27648)
  ushort_t* const B2s = U;                          // 128 x CP after GEMM1
  const int tid  = threadIdx.x;
  const int wave = tid >> 6, lane = tid & 63;
  const int l15  = lane & 15, quad = lane >> 4;
  const int row0 = blockIdx.x * 64;

  // ---- M1==2: in-block aggregation for this block's 64 nodes -> Cs ----
  if (M1 == 2){
    const int grp = tid >> 4;       // 16 groups of 16 lanes
    const int l   = tid & 15;
    const int gb  = tid & 48;       // group base lane within wave
    #pragma unroll 1
    for (int nb = 0; nb < 4; ++nb){
      int lrow = nb * 16 + grp;
      int node = row0 + lrow;
      uint4 o = make_uint4(0, 0, 0, 0);
      if (node < M){
        int p0 = rowptr[node], p1 = rowptr[node + 1];
        int dg = p1 - p0;
        float sa = sAi[node];
        float m = -1e30f, ssum = 0.f;
        float a[8];
        #pragma unroll
        for (int j = 0; j < 8; ++j) a[j] = 0.f;
        for (int c0 = 0; c0 < dg; c0 += 16){
          int cnt = dg - c0; if (cnt > 16) cnt = 16;
          bool ok = l < cnt;
          int pk = cpk[p0 + c0 + (ok ? l : 0)];
          float s = sa + sBi[pk & 0xFFFF] + sCi[pk >> 16];
          s = s > 0.f ? s : 0.2f * s;                    // leaky_relu(., 0.2)
          float sv = ok ? s : -1e30f;
          #pragma unroll
          for (int off = 8; off > 0; off >>= 1) sv = fmaxf(sv, __shfl_xor(sv, off, 16));
          float mn = fmaxf(m, sv);
          float corr = __expf(m - mn);
          ssum *= corr;
          #pragma unroll
          for (int j = 0; j < 8; ++j) a[j] *= corr;
          float ev = ok ? __expf(s - mn) : 0.f;
          float es = ev;
          #pragma unroll
          for (int off = 8; off > 0; off >>= 1) es += __shfl_xor(es, off, 16);
          ssum += es;
          m = mn;
          int png = ok ? pk : 0;
          for (int e = 0; e < cnt; e += 4){              // tails neutralized by ev=0
            int b0l = gb + e;
            int pe0 = __shfl(png, b0l,     64), pe1 = __shfl(png, b0l + 1, 64);
            int pe2 = __shfl(png, b0l + 2, 64), pe3 = __shfl(png, b0l + 3, 64);
            float e0 = __shfl(ev, b0l,     64), e1 = __shfl(ev, b0l + 1, 64);
            float e2 = __shfl(ev, b0l + 2, 64), e3 = __shfl(ev, b0l + 3, 64);
            uint4 u0 = *reinterpret_cast<const uint4*>(WxG + (size_t)(pe0 & 0xFFFF) * 128 + l * 8);
            uint4 u1 = *reinterpret_cast<const uint4*>(WxG + (size_t)(pe1 & 0xFFFF) * 128 + l * 8);
            uint4 u2 = *reinterpret_cast<const uint4*>(WxG + (size_t)(pe2 & 0xFFFF) * 128 + l * 8);
            uint4 u3 = *reinterpret_cast<const uint4*>(WxG + (size_t)(pe3 & 0xFFFF) * 128 + l * 8);
            a[0] += e0 * b2f_lo(u0.x); a[1] += e0 * b2f_hi(u0.x);
            a[2] += e0 * b2f_lo(u0.y); a[3] += e0 * b2f_hi(u0.y);
            a[4] += e0 * b2f_lo(u0.z); a[5] += e0 * b2f_hi(u0.z);
            a[6] += e0 * b2f_lo(u0.w); a[7] += e0 * b2f_hi(u0.w);
            a[0] += e1 * b2f_lo(u1.x); a[1] += e1 * b2f_hi(u1.x);
            a[2] += e1 * b2f_lo(u1.y); a[3] += e1 * b2f_hi(u1.y);
            a[4] += e1 * b2f_lo(u1.z); a[5] += e1 * b2f_hi(u1.z);
            a[6] += e1 * b2f_lo(u1.w); a[7] += e1 * b2f_hi(u1.w);
            a[0] += e2 * b2f_lo(u2.x); a[1] += e2 * b2f_hi(u2.x);
            a[2] += e2 * b2f_lo(u2.y); a[3] += e2 * b2f_hi(u2.y);
            a[4] += e2 * b2f_lo(u2.z); a[5] += e2 * b2f_hi(u2.z);
            a[6] += e2 * b2f_lo(u2.w); a[7] += e2 * b2f_hi(u2.w);
            a[0] += e3 * b2f_lo(u3.x); a[1] += e3 * b2f_hi(u3.x);
            a[2] += e3 * b2f_lo(u3.y); a[3] += e3 * b2f_hi(u3.y);
            a[4] += e3 * b2f_lo(u3.z); a[5] += e3 * b2f_hi(u3.z);
            a[6] += e3 * b2f_lo(u3.w); a[7] += e3 * b2f_hi(u3.w);
          }
        }
        float inv = (dg > 0) ? 1.f / ssum : 0.f;        // degree-0 -> zero row
        o.x = cvtpk(a[0] * inv, a[1] * inv);
        o.y = cvtpk(a[2] * inv, a[3] * inv);
        o.z = cvtpk(a[4] * inv, a[5] * inv);
        o.w = cvtpk(a[6] * inv, a[7] * inv);
      }
      *reinterpret_cast<uint4*>(&Cs[lrow * CP + l * 8]) = o;   // cols l*8..l*8+7
    }
  }

  f32x4 acc[8];
  #pragma unroll
  for (int t = 0; t < 8; ++t) acc[t] = (f32x4){0.f, 0.f, 0.f, 0.f};

  // ================= GEMM 1: A[M x K1] @ W1^T, BK=64, prefetched =================
  const int ar = tid >> 2, aq = tid & 3;     // A: row 0..63, 16-elem seg
  const int agrow = row0 + ar;
  const bool aok = agrow < M;
  const int awoff = ar * SP + aq * 16;
  const int bn = tid >> 1, bs = (tid & 1) * 32;   // B: n-row, 32-elem half
  const ushort_t* bsrc = Wb1 + (size_t)bn * K1 + bs;

  float4 pf0, pf1, pf2, pf3;
  uint4  pu0, pu1;
  uint4  pb0, pb1, pb2, pb3;
  pf0 = pf1 = pf2 = pf3 = make_float4(0.f, 0.f, 0.f, 0.f);
  pu0 = pu1 = make_uint4(0, 0, 0, 0);

#define ISSUE_A(kk) do{ if (aok){                                               \
    if constexpr (AFP32){                                                       \
      const float* ap_ = (const float*)Ap + (size_t)agrow * K1 + (kk) + aq * 16; \
      pf0 = *reinterpret_cast<const float4*>(ap_);                              \
      pf1 = *reinterpret_cast<const float4*>(ap_ + 4);                          \
      pf2 = *reinterpret_cast<const float4*>(ap_ + 8);                          \
      pf3 = *reinterpret_cast<const float4*>(ap_ + 12);                         \
    } else {                                                                    \
      const ushort_t* apb_ = (const ushort_t*)Ap + (size_t)agrow * K1 + (kk) + aq * 16; \
      pu0 = *reinterpret_cast<const uint4*>(apb_);                              \
      pu1 = *reinterpret_cast<const uint4*>(apb_ + 8);                          \
    } } }while(0)

#define ISSUE_B(kk) do{                                                         \
    pb0 = *reinterpret_cast<const uint4*>(bsrc + (kk));                         \
    pb1 = *reinterpret_cast<const uint4*>(bsrc + (kk) + 8);                     \
    pb2 = *reinterpret_cast<const uint4*>(bsrc + (kk) + 16);                    \
    pb3 = *reinterpret_cast<const uint4*>(bsrc + (kk) + 24);                    \
  }while(0)

#define WRITE_AB() do{                                                          \
    uint4 av0_, av1_;                                                           \
    if constexpr (AFP32){                                                       \
      av0_.x = cvtpk(pf0.x, pf0.y); av0_.y = cvtpk(pf0.z, pf0.w);               \
      av0_.z = cvtpk(pf1.x, pf1.y); av0_.w = cvtpk(pf1.z, pf1.w);               \
      av1_.x = cvtpk(pf2.x, pf2.y); av1_.y = cvtpk(pf2.z, pf2.w);               \
      av1_.z = cvtpk(pf3.x, pf3.y); av1_.w = cvtpk(pf3.z, pf3.w);               \
    } else { av0_ = pu0; av1_ = pu1; }                                          \
    *reinterpret_cast<uint4*>(&As[awoff])     = av0_;                           \
    *reinterpret_cast<uint4*>(&As[awoff + 8]) = av1_;                           \
    *reinterpret_cast<uint4*>(&Bs[bn * SP + bs])      = pb0;                    \
    *reinterpret_cast<uint4*>(&Bs[bn * SP + bs + 8])  = pb1;                    \
    *reinterpret_cast<uint4*>(&Bs[bn * SP + bs + 16]) = pb2;                    \
    *reinterpret_cast<uint4*>(&Bs[bn * SP + bs + 24]) = pb3;                    \
  }while(0)

  ISSUE_A(0); ISSUE_B(0);
  for (int t = 0; t < NT; ++t){
    WRITE_AB();
    __syncthreads();
    if (t + 1 < NT){ ISSUE_A((t + 1) * BK); ISSUE_B((t + 1) * BK); }
    bf16x8 af0 = *reinterpret_cast<const bf16x8*>(&As[(wave * 16 + l15) * SP + quad * 8]);
    bf16x8 af1 = *reinterpret_cast<const bf16x8*>(&As[(wave * 16 + l15) * SP + 32 + quad * 8]);
    #pragma unroll
    for (int tt = 0; tt < 8; ++tt){
      bf16x8 b0 = *reinterpret_cast<const bf16x8*>(&Bs[(tt * 16 + l15) * SP + quad * 8]);
      acc[tt] = __builtin_amdgcn_mfma_f32_16x16x32_bf16(af0, b0, acc[tt], 0, 0, 0);
      bf16x8 b1 = *reinterpret_cast<const bf16x8*>(&Bs[(tt * 16 + l15) * SP + 32 + quad * 8]);
      acc[tt] = __builtin_amdgcn_mfma_f32_16x16x32_bf16(af1, b1, acc[tt], 0, 0, 0);
    }
    __syncthreads();
  }
#undef ISSUE_A
#undef ISSUE_B
#undef WRITE_AB

  // ---- issue GEMM2 B loads first (latency hides under epilogue-1 VALU) ----
  uint4 wreg[8];
  #pragma unroll
  for (int i = 0; i < 8; ++i){
    int idx = tid + 256 * i;                 // 2048 chunks of 8 bf16
    int rr = idx >> 4, c8 = idx & 15;
    wreg[i] = *reinterpret_cast<const uint4*>(Wb2 + (size_t)rr * 128 + c8 * 8);
  }

  // ---- epilogue 1: C/D map col=t*16+l15, local row lr=wave*16+quad*4+r ----
  float vv[8][4];
  #pragma unroll
  for (int t = 0; t < 8; ++t){
    #pragma unroll
    for (int r = 0; r < 4; ++r){
      int lr  = wave * 16 + quad * 4 + r;
      int col = t * 16 + l15;
      float v = acc[t][r];
      if (M1 == 1){
        v += bias1[col];
        v = v > 0.f ? v : 0.01f * v;
      } else { // M1 == 2
        v += b2f_us(Cs[lr * CP + col]);      // same cell this thread rewrites below
        v = v > 0.f ? v : __expf(v) - 1.f;
      }
      vv[t][r] = v;
    }
  }
  // write staged B2 (As/Bs region dead after last k-loop barrier)
  #pragma unroll
  for (int i = 0; i < 8; ++i){
    int idx = tid + 256 * i;
    int rr = idx >> 4, c8 = idx & 15;
    *reinterpret_cast<uint4*>(&B2s[rr * CP + c8 * 8]) = wreg[i];
  }
  if (NORM){
    #pragma unroll
    for (int r = 0; r < 4; ++r){
      float ss = 0.f;
      #pragma unroll
      for (int t = 0; t < 8; ++t) ss += vv[t][r] * vv[t][r];
      #pragma unroll
      for (int off = 1; off < 16; off <<= 1) ss += __shfl_xor(ss, off, 64);
      float sc = 1.f / fmaxf(sqrtf(ss), 1e-12f);
      #pragma unroll
      for (int t = 0; t < 8; ++t) vv[t][r] *= sc;
    }
  }
  #pragma unroll
  for (int t = 0; t < 8; t += 2){
    #pragma unroll
    for (int r = 0; r < 4; ++r){
      int lr  = wave * 16 + quad * 4 + r;
      int c0  = t * 16 + l15, c1 = c0 + 16;
      uint_t pr = cvtpk(vv[t][r], vv[t + 1][r]);
      Cs[lr * CP + c0] = (ushort_t)pr;
      Cs[lr * CP + c1] = (ushort_t)(pr >> 16);
      if (STORE1){
        int grow = row0 + lr;
        if (grow < M){
          out1[(size_t)grow * 128 + c0] = (ushort_t)pr;
          out1[(size_t)grow * 128 + c1] = (ushort_t)(pr >> 16);
        }
      }
    }
  }
  __syncthreads();

  // ================= GEMM 2: Cs[64 x 128] @ W2^T, fully staged =================
  #pragma unroll
  for (int t = 0; t < 8; ++t) acc[t] = (f32x4){0.f, 0.f, 0.f, 0.f};
  #pragma unroll
  for (int kk = 0; kk < 4; ++kk){
    bf16x8 af2 = *reinterpret_cast<const bf16x8*>(&Cs[(wave * 16 + l15) * CP + kk * 32 + quad * 8]);
    #pragma unroll
    for (int t = 0; t < 8; ++t){
      bf16x8 bfr = *reinterpret_cast<const bf16x8*>(&B2s[(t * 16 + l15) * CP + kk * 32 + quad * 8]);
      acc[t] = __builtin_amdgcn_mfma_f32_16x16x32_bf16(af2, bfr, acc[t], 0, 0, 0);
    }
  }

  // ---- epilogue 2 ----
  if (M2 == 1){
    #pragma unroll
    for (int t = 0; t < 8; ++t){
      #pragma unroll
      for (int r = 0; r < 4; ++r){
        int grow = row0 + wave * 16 + quad * 4 + r;
        if (grow >= M) continue;
        int col = t * 16 + l15;
        float v = acc[t][r] + vec2[col];
        v = v > 0.f ? v : 0.01f * v;
        ((float*)out2)[(size_t)grow * 128 + col] = v;
      }
    }
  } else { // M2 == 3: bf16 out + per-row sA/sB
    #pragma unroll
    for (int t = 0; t < 8; t += 2){
      #pragma unroll
      for (int r = 0; r < 4; ++r){
        int grow = row0 + wave * 16 + quad * 4 + r;
        if (grow >= M) continue;
        int c0 = t * 16 + l15;
        uint_t pr = cvtpk(acc[t][r], acc[t + 1][r]);
        ((ushort_t*)out2)[(size_t)grow * 128 + c0]      = (ushort_t)pr;
        ((ushort_t*)out2)[(size_t)grow * 128 + c0 + 16] = (ushort_t)(pr >> 16);
      }
    }
    #pragma unroll
    for (int r = 0; r < 4; ++r){
      float pa = 0.f, pb = 0.f;
      #pragma unroll
      for (int t = 0; t < 8; ++t){
        int col = t * 16 + l15;
        pa += acc[t][r] * vec2[col];
        pb += acc[t][r] * vec2[128 + col];
      }
      #pragma unroll
      for (int off = 1; off < 16; off <<= 1){
        pa += __shfl_xor(pa, off, 64);
        pb += __shfl_xor(pb, off, 64);
      }
      int grow = row0 + wave * 16 + quad * 4 + r;
      if (l15 == r && grow < M){ sAo[grow] = pa; sBo[grow] = pb; }
    }
  }
}

// ---- distinctly-named kernels per stage (rocprof visibility) ----
__global__ __launch_bounds__(256) void g1_k(
    const void* Ap, const ushort_t* Wb1, const float* bias1,
    ushort_t* out1, const ushort_t* Wb2, const float* vec2,
    void* out2, float* sAo, float* sBo, int M){
  gfused_impl<KIN, 1, true, false, true, 3>(Ap, Wb1, bias1, nullptr, nullptr,
      nullptr, nullptr, nullptr, nullptr, out1, Wb2, vec2, out2, sAo, sBo, M);
}
__global__ __launch_bounds__(256) void g2_k(
    const void* Ap, const ushort_t* Wb1,
    const ushort_t* WxG, const int* rowptr, const int* cpk,
    const float* sAi, const float* sBi, const float* sCi,
    ushort_t* out1, const ushort_t* Wb2, const float* vec2,
    void* out2, float* sAo, float* sBo, int M){
  gfused_impl<H, 2, false, false, true, 3>(Ap, Wb1, nullptr, WxG, rowptr, cpk,
      sAi, sBi, sCi, out1, Wb2, vec2, out2, sAo, sBo, M);
}
__global__ __launch_bounds__(256) void g3_k(
    const void* Ap, const ushort_t* Wb1,
    const ushort_t* WxG, const int* rowptr, const int* cpk,
    const float* sAi, const float* sBi, const float* sCi,
    const ushort_t* Wb2, const float* vec2, void* out2, int M){
  gfused_impl<H, 2, false, true, false, 1>(Ap, Wb1, nullptr, WxG, rowptr, cpk,
      sAi, sBi, sCi, nullptr, Wb2, vec2, out2, nullptr, nullptr, M);
}

} // namespace

extern "C" void kernel_launch(void* const* d_in, const int* in_sizes, int n_in,
                              void* d_out, int out_size, void* d_ws, size_t ws_size,
                              hipStream_t stream)
{
  const float* x     = (const float*)d_in[0];
  const int*   eidx  = (const int*)d_in[1];
  const int*   et    = (const int*)d_in[2];
  const float* l1W   = (const float*)d_in[3];
  const float* l1b   = (const float*)d_in[4];
  const float* l2W   = (const float*)d_in[5];
  const float* l2b   = (const float*)d_in[6];
  const float* W1    = (const float*)d_in[7];
  const float* Wr1   = (const float*)d_in[8];
  const float* a1    = (const float*)d_in[9];
  const float* Wres1 = (const float*)d_in[10];
  const float* rel1  = (const float*)d_in[11];
  const float* W2    = (const float*)d_in[12];
  const float* Wr2   = (const float*)d_in[13];
  const float* a2    = (const float*)d_in[14];
  const float* Wres2 = (const float*)d_in[15];
  const float* rel2  = (const float*)d_in[16];
  float* outp = (float*)d_out;

  const int* esrc = eidx;        // edge_index[0]
  const int* edst = eidx + E;    // edge_index[1]

  // -------- workspace layout --------
  float* f = (float*)d_ws;
  size_t o = 0;
  float* sA1  = f + o; o += N;
  float* sB1  = f + o; o += N;
  float* sA2  = f + o; o += N;
  float* sB2  = f + o; o += N;
  float* sC1  = f + o; o += 8;
  float* sC2  = f + o; o += 8;
  ushort_t* us = (ushort_t*)(f + o);
  size_t ou = 0;
  ushort_t* b0   = us + ou; ou += (size_t)N * H;    // h0 bf16
  ushort_t* b1   = us + ou; ou += (size_t)N * H;    // h1 bf16
  ushort_t* WxA  = us + ou; ou += (size_t)N * H;    // Wx layer-1 bf16
  ushort_t* WxB  = us + ou; ou += (size_t)N * H;    // Wx layer-2 bf16
  ushort_t* wtsb = us + ou; ou += (size_t)H * KIN + 5 * H * H;
  ushort_t* l1Wb = wtsb;
  ushort_t* W1b  = wtsb + H * KIN;
  ushort_t* R1b  = W1b + H * H;
  ushort_t* W2b  = R1b + H * H;
  ushort_t* R2b  = W2b + H * H;
  ushort_t* l2Wb = R2b + H * H;
  if (ou & 1) ou += 1;
  int* wi = (int*)(us + ou);
  size_t oi = 0;
  int* deg    = wi + oi; oi += N;
  int* rowptr = wi + oi; oi += N + 1;
  int* cursor = wi + oi; oi += N;
  int* bsums  = wi + oi; oi += 256;
  int* boffs  = wi + oi; oi += 256;
  int* cpk    = wi + oi; oi += E;

  const int EB    = (E + 255) / 256;
  const int NB256 = (N + 255) / 256;
  const int GB    = (N + 63) / 64;

  // -------- prep (deg zero via memset; weight cvt + relsc + degcount fused) --------
  hipMemsetAsync(deg, 0, (size_t)N * sizeof(int), stream);
  prep_k<<<706 + EB, 256, 0, stream>>>(l1W, W1, Wres1, W2, Wres2, l2W, wtsb, deg,
                                       edst, rel1, Wr1, a1, sC1, rel2, Wr2, a2, sC2);
  scan1_k<<<NB256, 256, 0, stream>>>(deg, rowptr, bsums, N);
  scan2_k<<<1, 256, 0, stream>>>(bsums, boffs, NB256);
  scan3_k<<<NB256, 256, 0, stream>>>(rowptr, boffs, cursor, N, E);
  fill_k<<<EB, 256, 0, stream>>>(esrc, edst, et, cursor, cpk);

  // -------- G1: h0 = leaky(x@l1W^T+b) -> b0;  Wx1 = h0@W1^T -> WxA (+sA1/sB1) --------
  g1_k<<<GB, 256, 0, stream>>>(x, l1Wb, l1b, b0, W1b, a1, WxA, sA1, sB1, N);

  // -------- G2: agg1 (in-block); h1 = elu(agg1 + b0@R1^T) -> b1; Wx2 -> WxB --------
  g2_k<<<GB, 256, 0, stream>>>(b0, R1b, WxA, rowptr, cpk, sA1, sB1, sC1,
                               b1, W2b, a2, WxB, sA2, sB2, N);

  // -------- G3: agg2 (in-block); h2 = normalize(elu(agg2 + b1@R2^T)); out --------
  g3_k<<<GB, 256, 0, stream>>>(b1, R2b, WxB, rowptr, cpk, sA2, sB2, sC2,
                               l2Wb, l2b, outp, N);
}